// Round 7
// baseline (1355.515 us; speedup 1.0000x reference)
//
#include <hip/hip_runtime.h>
#include <stdint.h>

#define T_STEPS 14
#define B_DIM   4096
#define I_DIM   2048
#define H_DIM   1024
#define O_DIM   128
#define K_TOT   3072   // I_DIM + H_DIM
#define ZBYTES  ((size_t)B_DIM * H_DIM)

// fixed-point scale 2^25: |w|max ~0.16 -> |W| ~5.1M, 3 signed base-256 digits exact
#define WSCALE_F 33554432.0f

typedef __bf16  bf16x8  __attribute__((ext_vector_type(8)));
typedef float   floatx4 __attribute__((ext_vector_type(4)));
typedef int     int4v   __attribute__((ext_vector_type(4)));
typedef int     int16v  __attribute__((ext_vector_type(16)));
typedef unsigned long long u64;

__device__ __forceinline__ uint16_t f2bf_rne(float f) {
    uint32_t u = __float_as_uint(f);
    u += 0x7fffu + ((u >> 16) & 1u);
    return (uint16_t)(u >> 16);
}
__device__ __forceinline__ float bf2f(uint16_t h) {
    return __uint_as_float(((uint32_t)h) << 16);
}

// async global->LDS, 16B/lane; LDS dest = wave-uniform base + lane*16 (implicit)
__device__ __forceinline__ void gload_lds16(const void* g, void* l) {
    __builtin_amdgcn_global_load_lds((__attribute__((address_space(1))) void*)g,
                                     (__attribute__((address_space(3))) void*)l, 16, 0, 0);
}

// ================= fragment-order layouts, BK=128 (validated r11) =================
// B digits: WB[nt(32)][ktw(24)][s(3)][kk(4)][lane(64)][16B]      (12 KB chunks)
// A spikes: Xall[t][mIdx(32)][ktx(16)][group(4)][kk(4)][lane(64)][16B]  (16 KB chunks)
// Z state:  ZS[t][mIdx(32)][ktz(8)][group(4)][kk(4)][lane(64)][16B]     (16 KB chunks)
// element (row = group*32 + (lane&31), k = kt*128 + kk*32 + (lane>>5)*16 + j)

__global__ void split_w_kernel(const float* __restrict__ w_in, const float* __restrict__ w_rec,
                               int8_t* __restrict__ WB) {
    int idx = blockIdx.x * 256 + threadIdx.x;          // over H_DIM*K_TOT
    int h = idx / K_TOT;
    int k = idx - h * K_TOT;
    float w = (k < I_DIM) ? w_in[(size_t)h * I_DIM + k]
                          : w_rec[(size_t)h * H_DIM + (k - I_DIM)];
    int W  = __float2int_rn(w * WSCALE_F);
    int d0 = (int8_t)(W & 0xFF);
    int r1 = (W - d0) >> 8;
    int d1 = (int8_t)(r1 & 0xFF);
    int d2 = (r1 - d1) >> 8;                           // |d2| <= ~80
    int nt = h >> 5, n32 = h & 31;
    int ktw = k >> 7, k128 = k & 127;
    int kk = k128 >> 5, half = (k128 >> 4) & 1, j = k128 & 15;
    int lane = half * 32 + n32;
    size_t base = (size_t)(nt * 24 + ktw) * 12288 + kk * 1024 + lane * 16 + j;
    WB[base] = (int8_t)d0; WB[base + 4096] = (int8_t)d1; WB[base + 8192] = (int8_t)d2;
}

// ---------- out_w -> bf16 hi/mid/lo (validated) ----------
__global__ void split_ow_kernel(const float* __restrict__ out_w, uint16_t* __restrict__ OW3) {
    int idx = blockIdx.x * 256 + threadIdx.x;          // over O_DIM*H_DIM
    float w = out_w[idx];
    uint16_t hi = f2bf_rne(w);
    float r1 = w - bf2f(hi);
    uint16_t mid = f2bf_rne(r1);
    float r2 = r1 - bf2f(mid);
    uint16_t lo = f2bf_rne(r2);
    const size_t S = (size_t)O_DIM * H_DIM;
    OW3[idx] = hi; OW3[idx + S] = mid; OW3[idx + 2 * S] = lo;
}

// ---------- x fp32 -> i8, ALL timesteps, BK=128 fragment-order (validated r11) ----------
__global__ void cvt_x_kernel(const float* __restrict__ x, int8_t* __restrict__ xb) {
    size_t gid = (size_t)blockIdx.x * 256 + threadIdx.x;   // one 16B output granule each
    int g = (int)(gid & 1023);                             // granule within 16KB chunk
    size_t chunk = gid >> 10;                              // (t*32 + mIdx)*16 + kt
    int kt   = (int)(chunk & 15);
    int mIdx = (int)((chunk >> 4) & 31);
    int t    = (int)(chunk >> 9);
    int group = g >> 8, kk = (g >> 6) & 3, lane = g & 63;
    int half = lane >> 5, row32 = lane & 31;
    int b = mIdx * 128 + group * 32 + row32;
    int k = kt * 128 + kk * 32 + half * 16;
    const float4* src = (const float4*)(x + ((size_t)t * B_DIM + b) * I_DIM + k);
    union { int8_t bytes[16]; int4v v; } u;
#pragma unroll
    for (int q = 0; q < 4; ++q) {
        float4 f = src[q];
        u.bytes[q * 4 + 0] = (int8_t)(f.x > 0.5f);
        u.bytes[q * 4 + 1] = (int8_t)(f.y > 0.5f);
        u.bytes[q * 4 + 2] = (int8_t)(f.z > 0.5f);
        u.bytes[q * 4 + 3] = (int8_t)(f.w > 0.5f);
    }
    ((int4v*)xb)[gid] = u.v;
}

// ---------- zero the group-sync counters (32 groups x 13 steps x 128B stride) ----------
// agent-scope stores: zeros reach the coherence point regardless of replay history
__global__ void zero_cnt_kernel(uint32_t* __restrict__ cnt) {
    __hip_atomic_store(&cnt[blockIdx.x * 256 + threadIdx.x], 0u,
                       __ATOMIC_RELAXED, __HIP_MEMORY_SCOPE_AGENT);
}

// ================= fully pipelined K-step (R7: A-register double-buffer) =================
// BOTH operands prefetched one iteration ahead:
//  - A(kt+1) -> aNxt regs (4 global_load_dwordx4), consumed next iter from aCur
//  - B(kt+1) -> LDS nxt (3 gload_lds16)
// Per iter exactly 7 vmem ops are issued; vmcnt(7) drains the PREVIOUS iter's 7
// (A(kt) in regs + B(kt) in LDS) while this iter's 7 stay in flight across the raw
// s_barrier. A-load latency (L2 ~200cy / HBM ~900cy) thus hides under a full iter of
// MFMA instead of sitting on the critical path (R6 post-mortem: that latency was the
// ~3200cy/iter gap keeping MfmaUtil at 34%). Counting is window-exact between the
// "memory"-clobber asms; older leftover ops only make the wait stricter (safe).
__device__ __forceinline__ void loadA(const int8_t* __restrict__ aP, int4v (&a)[4]) {
    a[0] = *(const int4v*)(aP);
    a[1] = *(const int4v*)(aP + 1024);
    a[2] = *(const int4v*)(aP + 2048);
    a[3] = *(const int4v*)(aP + 3072);
}

__device__ __forceinline__ void stage_b0(const int8_t* __restrict__ bChunk0,
                                         int8_t* sB0, int wave, int lane) {
    gload_lds16(bChunk0 + (size_t)wave * 1024 + lane * 16,       sB0 + wave * 1024);
    gload_lds16(bChunk0 + (size_t)(4 + wave) * 1024 + lane * 16, sB0 + (4 + wave) * 1024);
    gload_lds16(bChunk0 + (size_t)(8 + wave) * 1024 + lane * 16, sB0 + (8 + wave) * 1024);
}

__device__ __forceinline__ void lif_iter_p(const int8_t* __restrict__ aPn,  // next A frag (per-thread) or null
                                           const int8_t* __restrict__ bPn,  // next B chunk (12KB) or null
                                           const int8_t* cur, int8_t* nxt,  // LDS ping-pong
                                           int4v (&aC)[4], int4v (&aN)[4],  // A cur/next regs
                                           int wave, int lane, bool stage_next,
                                           int16v (&acc)[3]) {
    if (stage_next) {
        loadA(aPn, aN);                                    // A(kt+1) -> regs
        gload_lds16(bPn + (size_t)wave * 1024 + lane * 16,       nxt + wave * 1024);
        gload_lds16(bPn + (size_t)(4 + wave) * 1024 + lane * 16, nxt + (4 + wave) * 1024);
        gload_lds16(bPn + (size_t)(8 + wave) * 1024 + lane * 16, nxt + (8 + wave) * 1024);
        __builtin_amdgcn_sched_barrier(0);
        asm volatile("s_waitcnt vmcnt(7)" ::: "memory");   // drain A(kt)+B(kt); keep this iter's 7 in flight
    } else {
        asm volatile("s_waitcnt vmcnt(0)" ::: "memory");   // tail: drain last iter's A+B
    }
    __builtin_amdgcn_s_barrier();                          // all waves' B(kt) landed
    __builtin_amdgcn_sched_barrier(0);
#pragma unroll
    for (int kk = 0; kk < 4; ++kk) {
#pragma unroll
        for (int s = 0; s < 3; ++s) {
            int4v bF = *(const int4v*)(cur + s * 4096 + kk * 1024 + lane * 16);
            acc[s] = __builtin_amdgcn_mfma_i32_32x32x32_i8(aC[kk], bF, acc[s], 0, 0, 0);
        }
    }
    asm volatile("s_waitcnt lgkmcnt(0)" ::: "memory");     // reads of 'cur' done
    __builtin_amdgcn_s_barrier();                          // safe to overwrite 'cur' next iter
}

// Contract: caller has ISSUED A(0)->aA and B(0)->sB0 (completion enforced by the first
// iter's vmcnt(7) / an intervening __syncthreads). Ends with ping-pong at sB1; sB0 free.
template<int NKT>
__device__ __forceinline__ void run_phase(const int8_t* __restrict__ aW,   // per-thread frag base, +kt*16384
                                          const int8_t* __restrict__ bC,   // B chunk base, +kt*12288
                                          int8_t* sB0, int8_t* sB1,
                                          int4v (&aA)[4], int4v (&aB)[4],
                                          int wave, int lane, int16v (&acc)[3]) {
#pragma unroll 1
    for (int kt = 0; kt + 2 < NKT; kt += 2) {
        lif_iter_p(aW + (size_t)(kt + 1) * 16384, bC + (size_t)(kt + 1) * 12288,
                   sB0, sB1, aA, aB, wave, lane, true, acc);
        lif_iter_p(aW + (size_t)(kt + 2) * 16384, bC + (size_t)(kt + 2) * 12288,
                   sB1, sB0, aB, aA, wave, lane, true, acc);
    }
    lif_iter_p(aW + (size_t)(NKT - 1) * 16384, bC + (size_t)(NKT - 1) * 12288,
               sB0, sB1, aA, aB, wave, lane, true, acc);
    lif_iter_p(nullptr, nullptr, sB1, sB0, aB, aA, wave, lane, false, acc);
}

// ================= persistent LIF: all 14 steps, ONE PLAIN launch =================
// PLAIN launch (graph-capture-safe). Co-residency of all 1024 blocks by exact-fit
// capacity: <=128 VGPR (launch_bounds cap), 28KB LDS x4 = 112KB <= 160KB, 16 waves/CU
// <= 32 -> 4 blocks/CU x 256 CU = 1024 = grid (validated on HW by R1-R3 coop checks).
//
// Coherence protocol — NO per-step fence (validated R6: passes through timed path):
//  - Replay staleness: dispatch boundaries perform L2 writeback+invalidate (direct
//    evidence: R0 fallback passes with plain dirty-L2 cross-kernel stores under graph
//    replay). No ZS line survives replay N into replay N+1's dispatch.
//  - Within one execution: ZS[t] is virgin until producers' agent-scope 8B atomic
//    stores (LLC write-through, vmcnt-acked before the flag add) land; consumers spin
//    on the flag + __syncthreads before touching them -> plain CACHED loads are fresh
//    and keep full L1/L2 reuse.
//  - Flag spin: relaxed agent-scope atomic loads (LLC-direct, no invalidates -> W
//    stays L2-resident, mIdx groups drift freely; no lockstep miss storms).
__launch_bounds__(256, 4)
__global__ void lif_persist_kernel(const int8_t* __restrict__ Xall,
                                   const int8_t* __restrict__ WB,
                                   int8_t* __restrict__ ZS,      // 13 per-step z buffers
                                   uint16_t* __restrict__ Zbf,
                                   uint32_t* __restrict__ cnt) {
    __shared__ int8_t sB0[12288];   // [s(3)][kk(4)][lane(64)][16B]
    __shared__ int8_t sB1[12288];
    __shared__ int8_t sZ[4096];     // z repack staging

    const int tid  = threadIdx.x;
    const int wave = tid >> 6, lane = tid & 63;
    const int lane32 = lane & 31, hl = lane >> 5;

    // 2D parity swizzle (bijective on 0..1023; correctness-independent of XCD mapping)
    const int bid = blockIdx.x;
    const int xs = bid & 7, q = bid >> 3;
    const int mIdx = (xs & 1) * 16 + (q & 15);
    const int nt   = (xs >> 1) * 8 + (q >> 4);

    const int mBase = mIdx * 128, nBase = nt * 32;
    const int8_t* wbStrip = WB + (size_t)nt * 24 * 12288;
    const int fragOff = wave * 4096 + lane * 16;

    float vmem[16], isyn[16];
#pragma unroll
    for (int r = 0; r < 16; ++r) { vmem[r] = 0.0f; isyn[r] = 0.0f; }

    int4v aA[4], aB[4];

    // initial prestage: X(t=0) A(0) -> aA, B(0) -> sB0
    stage_b0(wbStrip, sB0, wave, lane);
    loadA(Xall + (size_t)mIdx * 16 * 16384 + fragOff, aA);

    for (int t = 0; t < T_STEPS; ++t) {
        int16v acc[3] = {};

        // ---- X phase: kt 0..15 (A(0)/B(0) prestaged by prior step's pre-epilogue) ----
        const int8_t* XtW = Xall + (size_t)t * ((size_t)B_DIM * I_DIM)
                          + (size_t)mIdx * 16 * 16384 + fragOff;
        run_phase<16>(XtW, wbStrip, sB0, sB1, aA, aB, wave, lane, acc);

        // ---- recurrent phase: needs z(t-1) from the 32 blocks of this mIdx group ----
        if (t > 0) {
            const int8_t* zbChunk = wbStrip + (size_t)16 * 12288;
            // prestage z-phase B(0) (W independent of z; latency hides under the spin)
            stage_b0(zbChunk, sB0, wave, lane);
            if (tid == 0) {
                const uint32_t* f = cnt + ((size_t)mIdx * 13 + (t - 1)) * 32;
                while (__hip_atomic_load((uint32_t*)f, __ATOMIC_RELAXED, __HIP_MEMORY_SCOPE_AGENT) < 32u)
                    __builtin_amdgcn_s_sleep(2);
            }
            __syncthreads();   // spin visible to all; full compiler barrier; drains B(0) stage
            const int8_t* zW = ZS + (size_t)(t - 1) * ZBYTES + (size_t)mIdx * 8 * 16384 + fragOff;
            loadA(zW, aA);     // A(0) of z phase (first iter's vmcnt(7) drains it)
            run_phase<8>(zW, zbChunk, sB0, sB1, aA, aB, wave, lane, acc);
        }

        // ---- prestage NEXT step's X-phase A(0)/B(0): fly during the epilogue, drained
        //      by the epilogue's __syncthreads (free latency hiding) ----
        if (t + 1 < T_STEPS) {
            stage_b0(wbStrip, sB0, wave, lane);
            loadA(Xall + (size_t)(t + 1) * ((size_t)B_DIM * I_DIM)
                  + (size_t)mIdx * 16 * 16384 + fragOff, aA);
        }

        // ---- LIF epilogue (registers): C/D row=(r&3)+8*(r>>2)+4*hl, col=lane32 ----
#pragma unroll
        for (int r = 0; r < 16; ++r) {
#pragma clang fp contract(off)
            // exact digit combine (|counts| < 2^24)
            float cur = (float)acc[2][r] * (1.0f / 512.0f)
                      + (float)acc[1][r] * (1.0f / 131072.0f)
                      + (float)acc[0][r] * (1.0f / 33554432.0f);
            int row = (r & 3) + 8 * (r >> 2) + 4 * hl;    // 0..31 (C/D layout)
            float v_dec = vmem[r] + 0.1f * ((0.0f - vmem[r]) + isyn[r]);
            float i_dec = isyn[r] - 0.2f * isyn[r];
            bool z = (v_dec > 1.0f);
            vmem[r] = z ? 0.0f : v_dec;                   // == (1-z)*v_dec + z*V_RESET exactly
            isyn[r] = i_dec + cur;
            if (t == T_STEPS - 1) {
                int b = mBase + wave * 32 + row;
                int h = nBase + lane32;
                Zbf[(size_t)b * H_DIM + h] = z ? (uint16_t)0x3F80 : (uint16_t)0;
            } else {
                // [group=wave][kk=nt&3][lane'=(lane32>>4)*32+row][j=lane32&15] into sZ
                sZ[wave * 1024 + ((lane32 >> 4) * 32 + row) * 16 + (lane32 & 15)]
                    = z ? (int8_t)1 : (int8_t)0;
            }
        }

        if (t < T_STEPS - 1) {
            __syncthreads();   // sZ complete (also drains prestaged A/B for next X phase)
            // repack: 16 contiguous bytes/thread -> two 8B agent-scope stores
            const u64* sp = (const u64*)&sZ[tid * 16];
            u64 v0 = sp[0], v1 = sp[1];
            int8_t* dst = ZS + (size_t)t * ZBYTES + ((size_t)mIdx * 8 + (nt >> 2)) * 16384
                        + (tid >> 6) * 4096 + (nt & 3) * 1024 + (tid & 63) * 16;
            __hip_atomic_store((u64*)dst,       v0, __ATOMIC_RELAXED, __HIP_MEMORY_SCOPE_AGENT);
            __hip_atomic_store((u64*)(dst + 8), v1, __ATOMIC_RELAXED, __HIP_MEMORY_SCOPE_AGENT);
            __syncthreads();   // drains vmcnt(0): all z-stores acked at the coherence point
            if (tid == 0)
                __hip_atomic_fetch_add(&cnt[((size_t)mIdx * 13 + t) * 32], 1u,
                                       __ATOMIC_RELAXED, __HIP_MEMORY_SCOPE_AGENT);
        }
    }
}

// ---------- output GEMM: out = z_T @ out_w^T + out_b (bf16x3) ----------
__launch_bounds__(256)
__global__ void out_gemm_kernel(const uint16_t* __restrict__ Zfin,  // [B][H_DIM] bf16
                                const uint16_t* __restrict__ OW3,   // [3][O_DIM][H_DIM] bf16
                                const float* __restrict__ out_b,
                                float* __restrict__ out) {
    __shared__ uint16_t sA[16 * 32];        // 1 KB : [row(16)][k(32)]
    __shared__ uint16_t sB[3][128 * 32];    // 24 KB: [s][row(128)][k(32)]

    const int tid  = threadIdx.x;
    const int wave = tid >> 6, lane = tid & 63;
    const int quad = lane >> 4, col = lane & 15;

    const int mBase = blockIdx.x * 16;

    floatx4 acc[2] = {};

    const int ldRow = lane >> 2;        // 0..15
    const int ldCol = (lane & 3) * 8;   // element offset (x2B = 16B)

    for (int kt = 0; kt < H_DIM / 32; ++kt) {
        const int kb = kt * 32;
        __syncthreads();
        if (wave == 0) {
            const uint16_t* g = Zfin + (size_t)(mBase + ldRow) * H_DIM + kb + ldCol;
            gload_lds16(g, &sA[0]);
        }
#pragma unroll
        for (int s = 0; s < 3; ++s) {
            const uint16_t* wsrc = OW3 + (size_t)s * O_DIM * H_DIM;
#pragma unroll
            for (int j = 0; j < 2; ++j) {
                const int rseg = j * 4 + wave;   // 0..7, 16 rows each
                const uint16_t* g = wsrc + (size_t)(rseg * 16 + ldRow) * H_DIM + kb + ldCol;
                gload_lds16(g, &sB[s][rseg * 16 * 32]);
            }
        }
        __syncthreads();

        bf16x8 aF = *reinterpret_cast<const bf16x8*>(&sA[col * 32 + quad * 8]);
#pragma unroll
        for (int s = 0; s < 3; ++s) {
#pragma unroll
            for (int ni = 0; ni < 2; ++ni) {
                int row = wave * 32 + ni * 16 + col;
                bf16x8 bF = *reinterpret_cast<const bf16x8*>(&sB[s][row * 32 + quad * 8]);
                acc[ni] = __builtin_amdgcn_mfma_f32_16x16x32_bf16(aF, bF, acc[ni], 0, 0, 0);
            }
        }
    }

    {
#pragma clang fp contract(off)
#pragma unroll
        for (int ni = 0; ni < 2; ++ni)
#pragma unroll
            for (int r = 0; r < 4; ++r) {
                int b = mBase + quad * 4 + r;          // C/D: row = quad*4 + reg
                int h = wave * 32 + ni * 16 + col;     //      col = lane&15
                out[(size_t)b * O_DIM + h] = acc[ni][r] + out_b[h];
            }
    }
}

extern "C" void kernel_launch(void* const* d_in, const int* in_sizes, int n_in,
                              void* d_out, int out_size, void* d_ws, size_t ws_size,
                              hipStream_t stream) {
    const float* x     = (const float*)d_in[0];
    const float* w_in  = (const float*)d_in[1];
    const float* w_rec = (const float*)d_in[2];
    const float* out_w = (const float*)d_in[3];
    const float* out_b = (const float*)d_in[4];
    float* out = (float*)d_out;

    char* ws = (char*)d_ws;
    size_t off = 0;
    int8_t*   WB   = (int8_t*)(ws + off);   off += (size_t)3 * H_DIM * K_TOT;        // 9.4 MB
    uint16_t* OW3  = (uint16_t*)(ws + off); off += (size_t)3 * O_DIM * H_DIM * 2;    // 0.8 MB
    int8_t*   Xall = (int8_t*)(ws + off);   off += (size_t)T_STEPS * B_DIM * I_DIM;  // 117 MB
    uint16_t* Zbf  = (uint16_t*)(ws + off); off += (size_t)B_DIM * H_DIM * 2;        // 8 MB
    int8_t*   ZS   = (int8_t*)(ws + off);   off += (size_t)13 * ZBYTES;              // 54.5 MB (per-step z)
    uint32_t* CNT  = (uint32_t*)(ws + off); off += (size_t)32 * 13 * 32 * 4;         // 53 KB

    split_w_kernel<<<(H_DIM * K_TOT) / 256, 256, 0, stream>>>(w_in, w_rec, WB);
    split_ow_kernel<<<(O_DIM * H_DIM) / 256, 256, 0, stream>>>(out_w, OW3);
    cvt_x_kernel<<<(int)(((size_t)T_STEPS * B_DIM * I_DIM / 16) / 256), 256, 0, stream>>>(x, Xall);
    zero_cnt_kernel<<<(32 * 13 * 32) / 256, 256, 0, stream>>>(CNT);

    // PLAIN launch: capture-safe. Co-residency by exact-fit occupancy (see kernel comment).
    lif_persist_kernel<<<dim3(1024), dim3(256), 0, stream>>>(Xall, WB, ZS, Zbf, CNT);

    out_gemm_kernel<<<B_DIM / 16, 256, 0, stream>>>(Zbf, OW3, out_b, out);
}

// Round 8
// 1295.440 us; speedup vs baseline: 1.0464x; 1.0464x over previous
//
#include <hip/hip_runtime.h>
#include <stdint.h>

#define T_STEPS 14
#define B_DIM   4096
#define I_DIM   2048
#define H_DIM   1024
#define O_DIM   128
#define K_TOT   3072   // I_DIM + H_DIM
#define ZBYTES  ((size_t)B_DIM * H_DIM)

// fixed-point scale 2^25: |w|max ~0.16 -> |W| ~5.1M, 3 signed base-256 digits exact
#define WSCALE_F 33554432.0f

typedef __bf16  bf16x8  __attribute__((ext_vector_type(8)));
typedef float   floatx4 __attribute__((ext_vector_type(4)));
typedef int     int4v   __attribute__((ext_vector_type(4)));
typedef int     int16v  __attribute__((ext_vector_type(16)));
typedef unsigned long long u64;

__device__ __forceinline__ uint16_t f2bf_rne(float f) {
    uint32_t u = __float_as_uint(f);
    u += 0x7fffu + ((u >> 16) & 1u);
    return (uint16_t)(u >> 16);
}
__device__ __forceinline__ float bf2f(uint16_t h) {
    return __uint_as_float(((uint32_t)h) << 16);
}

// async global->LDS, 16B/lane; LDS dest = wave-uniform base + lane*16 (implicit)
__device__ __forceinline__ void gload_lds16(const void* g, void* l) {
    __builtin_amdgcn_global_load_lds((__attribute__((address_space(1))) void*)g,
                                     (__attribute__((address_space(3))) void*)l, 16, 0, 0);
}

// ================= fragment-order layouts, BK=128 (validated r11) =================
// B digits: WB[nt(32)][ktw(24)][s(3)][kk(4)][lane(64)][16B]      (12 KB chunks)
// A spikes: Xall[t][mIdx(32)][ktx(16)][group(4)][kk(4)][lane(64)][16B]  (16 KB chunks)
// Z state:  ZS[t][mIdx(32)][ktz(8)][group(4)][kk(4)][lane(64)][16B]     (16 KB chunks)
// element (row = group*32 + (lane&31), k = kt*128 + kk*32 + (lane>>5)*16 + j)

__global__ void split_w_kernel(const float* __restrict__ w_in, const float* __restrict__ w_rec,
                               int8_t* __restrict__ WB) {
    int idx = blockIdx.x * 256 + threadIdx.x;          // over H_DIM*K_TOT
    int h = idx / K_TOT;
    int k = idx - h * K_TOT;
    float w = (k < I_DIM) ? w_in[(size_t)h * I_DIM + k]
                          : w_rec[(size_t)h * H_DIM + (k - I_DIM)];
    int W  = __float2int_rn(w * WSCALE_F);
    int d0 = (int8_t)(W & 0xFF);
    int r1 = (W - d0) >> 8;
    int d1 = (int8_t)(r1 & 0xFF);
    int d2 = (r1 - d1) >> 8;                           // |d2| <= ~80
    int nt = h >> 5, n32 = h & 31;
    int ktw = k >> 7, k128 = k & 127;
    int kk = k128 >> 5, half = (k128 >> 4) & 1, j = k128 & 15;
    int lane = half * 32 + n32;
    size_t base = (size_t)(nt * 24 + ktw) * 12288 + kk * 1024 + lane * 16 + j;
    WB[base] = (int8_t)d0; WB[base + 4096] = (int8_t)d1; WB[base + 8192] = (int8_t)d2;
}

// ---------- out_w -> bf16 hi/mid/lo (validated) ----------
__global__ void split_ow_kernel(const float* __restrict__ out_w, uint16_t* __restrict__ OW3) {
    int idx = blockIdx.x * 256 + threadIdx.x;          // over O_DIM*H_DIM
    float w = out_w[idx];
    uint16_t hi = f2bf_rne(w);
    float r1 = w - bf2f(hi);
    uint16_t mid = f2bf_rne(r1);
    float r2 = r1 - bf2f(mid);
    uint16_t lo = f2bf_rne(r2);
    const size_t S = (size_t)O_DIM * H_DIM;
    OW3[idx] = hi; OW3[idx + S] = mid; OW3[idx + 2 * S] = lo;
}

// ---------- x fp32 -> i8, ALL timesteps, BK=128 fragment-order (validated r11) ----------
__global__ void cvt_x_kernel(const float* __restrict__ x, int8_t* __restrict__ xb) {
    size_t gid = (size_t)blockIdx.x * 256 + threadIdx.x;   // one 16B output granule each
    int g = (int)(gid & 1023);                             // granule within 16KB chunk
    size_t chunk = gid >> 10;                              // (t*32 + mIdx)*16 + kt
    int kt   = (int)(chunk & 15);
    int mIdx = (int)((chunk >> 4) & 31);
    int t    = (int)(chunk >> 9);
    int group = g >> 8, kk = (g >> 6) & 3, lane = g & 63;
    int half = lane >> 5, row32 = lane & 31;
    int b = mIdx * 128 + group * 32 + row32;
    int k = kt * 128 + kk * 32 + half * 16;
    const float4* src = (const float4*)(x + ((size_t)t * B_DIM + b) * I_DIM + k);
    union { int8_t bytes[16]; int4v v; } u;
#pragma unroll
    for (int q = 0; q < 4; ++q) {
        float4 f = src[q];
        u.bytes[q * 4 + 0] = (int8_t)(f.x > 0.5f);
        u.bytes[q * 4 + 1] = (int8_t)(f.y > 0.5f);
        u.bytes[q * 4 + 2] = (int8_t)(f.z > 0.5f);
        u.bytes[q * 4 + 3] = (int8_t)(f.w > 0.5f);
    }
    ((int4v*)xb)[gid] = u.v;
}

// ---------- zero the group-sync counters (32 groups x 13 steps x 128B stride) ----------
// agent-scope stores: zeros reach the coherence point regardless of replay history
__global__ void zero_cnt_kernel(uint32_t* __restrict__ cnt) {
    __hip_atomic_store(&cnt[blockIdx.x * 256 + threadIdx.x], 0u,
                       __ATOMIC_RELAXED, __HIP_MEMORY_SCOPE_AGENT);
}

// ================= pipelined K-step (R8: zero-VGPR A prefetch + setprio) =================
// R7 post-mortem: a second A register buffer (+32 VGPR) overflowed the 64-VGPR
// allocation -> scratch traffic (WRITE_SIZE +122MB), net regression. This variant
// prefetches A(kt+1) into the SAME aA registers, issued AFTER the last MFMA that
// reads them (WAR gives ordering; sched_barrier(0) pins the issue point so the
// scheduler can't hoist the loads and recreate the live-range overlap).
// vmcnt audit (steady state, at top-of-iter wait): outstanding = B(kt):3 [prev top]
// + A(kt):4 [prev bottom] + B(kt+1):3 [just issued] = 10 -> vmcnt(3) drains A(kt)+B(kt),
// keeps B(kt+1) in flight across the barrier. Tail iter: vmcnt(0).
// A-load latency thus hides across the closing barrier instead of sitting between
// the opening barrier and the first MFMA (R6's exposure).
__device__ __forceinline__ void loadA(const int8_t* __restrict__ aP, int4v (&a)[4]) {
    a[0] = *(const int4v*)(aP);
    a[1] = *(const int4v*)(aP + 1024);
    a[2] = *(const int4v*)(aP + 2048);
    a[3] = *(const int4v*)(aP + 3072);
}

__device__ __forceinline__ void stage_b0(const int8_t* __restrict__ bChunk0,
                                         int8_t* sB0, int wave, int lane) {
    gload_lds16(bChunk0 + (size_t)wave * 1024 + lane * 16,       sB0 + wave * 1024);
    gload_lds16(bChunk0 + (size_t)(4 + wave) * 1024 + lane * 16, sB0 + (4 + wave) * 1024);
    gload_lds16(bChunk0 + (size_t)(8 + wave) * 1024 + lane * 16, sB0 + (8 + wave) * 1024);
}

__device__ __forceinline__ void lif_iter(const int8_t* __restrict__ aPn,  // A(kt+1) per-thread ptr or null
                                         const int8_t* __restrict__ bPn,  // B(kt+1) chunk or null
                                         const int8_t* cur, int8_t* nxt,  // LDS ping-pong
                                         int4v (&aA)[4],                  // A regs (single buffer)
                                         int wave, int lane, bool stage_next,
                                         int16v (&acc)[3]) {
    if (stage_next) {
        gload_lds16(bPn + (size_t)wave * 1024 + lane * 16,       nxt + wave * 1024);
        gload_lds16(bPn + (size_t)(4 + wave) * 1024 + lane * 16, nxt + (4 + wave) * 1024);
        gload_lds16(bPn + (size_t)(8 + wave) * 1024 + lane * 16, nxt + (8 + wave) * 1024);
        __builtin_amdgcn_sched_barrier(0);
        asm volatile("s_waitcnt vmcnt(3)" ::: "memory");   // drain A(kt)+B(kt); keep B(kt+1)
    } else {
        asm volatile("s_waitcnt vmcnt(0)" ::: "memory");   // tail: drain A(kt)+B(kt)
    }
    __builtin_amdgcn_s_barrier();                          // all waves' B(kt) landed
    __builtin_amdgcn_sched_barrier(0);
    __builtin_amdgcn_s_setprio(1);                         // T5: favor MFMA-entering wave
#pragma unroll
    for (int kk = 0; kk < 4; ++kk) {
#pragma unroll
        for (int s = 0; s < 3; ++s) {
            int4v bF = *(const int4v*)(cur + s * 4096 + kk * 1024 + lane * 16);
            acc[s] = __builtin_amdgcn_mfma_i32_32x32x32_i8(aA[kk], bF, acc[s], 0, 0, 0);
        }
    }
    __builtin_amdgcn_s_setprio(0);
    __builtin_amdgcn_sched_barrier(0);                     // pin A-issue AFTER its last reader
    if (aPn) loadA(aPn, aA);                               // A(kt+1) -> same regs, flies over barrier
    asm volatile("s_waitcnt lgkmcnt(0)" ::: "memory");     // reads of 'cur' done
    __builtin_amdgcn_s_barrier();                          // safe to overwrite 'cur' next iter
}

// Contract: caller has ISSUED A(0)->aA and B(0)->sB0 (first iter's vmcnt(3) or an
// intervening __syncthreads completes them). Phase starts cur=sB0, ends with sB0 free.
template<int NKT>
__device__ __forceinline__ void run_phase(const int8_t* __restrict__ aW,   // per-thread frag base, +kt*16384
                                          const int8_t* __restrict__ bC,   // B chunk base, +kt*12288
                                          int8_t* sB0, int8_t* sB1,
                                          int4v (&aA)[4],
                                          int wave, int lane, int16v (&acc)[3]) {
#pragma unroll 1
    for (int kt = 0; kt + 2 < NKT; kt += 2) {
        lif_iter(aW + (size_t)(kt + 1) * 16384, bC + (size_t)(kt + 1) * 12288,
                 sB0, sB1, aA, wave, lane, true, acc);
        lif_iter(aW + (size_t)(kt + 2) * 16384, bC + (size_t)(kt + 2) * 12288,
                 sB1, sB0, aA, wave, lane, true, acc);
    }
    lif_iter(aW + (size_t)(NKT - 1) * 16384, bC + (size_t)(NKT - 1) * 12288,
             sB0, sB1, aA, wave, lane, true, acc);
    lif_iter(nullptr, nullptr, sB1, sB0, aA, wave, lane, false, acc);
}

// ================= persistent LIF: all 14 steps, ONE PLAIN launch =================
// PLAIN launch (graph-capture-safe). Co-residency of all 1024 blocks by exact-fit
// capacity: 64 VGPR, 28KB LDS x4 = 112KB <= 160KB, 16 waves/CU <= 32 -> 4 blocks/CU
// x 256 CU = 1024 = grid (validated on HW by R1-R3 coop-launch checks).
//
// XCD mapping (R8): mIdx = (bid&7)*4 + (q&3), nt = q>>2  [bijective on 0..1023].
// Under round-robin bid->XCD, ALL 32 blocks of an mIdx group land on ONE XCD:
//  - X chunk fetched by exactly 1 XCD (was 4) -> HBM X traffic /4, 32x in-L2 reuse
//  - z produced & consumed intra-XCD; flag spin intra-XCD
//  - W strips refetch from LLC (9.4MB resident) as L2 streams past — LLC-hit cost.
// Mapping is perf-only; correctness never depends on which XCD a block runs on.
//
// Coherence protocol — NO per-step fence (validated R6 through the timed path):
//  - Replay staleness: dispatch boundaries perform L2 writeback+invalidate (direct
//    evidence: R0 fallback passes with plain dirty-L2 cross-kernel stores under graph
//    replay). No ZS line survives replay N into replay N+1's dispatch.
//  - Within one execution: ZS[t] is virgin until producers' agent-scope 8B atomic
//    stores (LLC write-through, vmcnt-acked before the flag add) land; consumers spin
//    on the flag + __syncthreads before touching them -> plain CACHED loads are fresh
//    and keep full L1/L2 reuse.
//  - Flag spin: relaxed agent-scope atomic loads (LLC-direct, no invalidates).
__launch_bounds__(256, 4)
__global__ void lif_persist_kernel(const int8_t* __restrict__ Xall,
                                   const int8_t* __restrict__ WB,
                                   int8_t* __restrict__ ZS,      // 13 per-step z buffers
                                   uint16_t* __restrict__ Zbf,
                                   uint32_t* __restrict__ cnt) {
    __shared__ int8_t sB0[12288];   // [s(3)][kk(4)][lane(64)][16B]
    __shared__ int8_t sB1[12288];
    __shared__ int8_t sZ[4096];     // z repack staging

    const int tid  = threadIdx.x;
    const int wave = tid >> 6, lane = tid & 63;
    const int lane32 = lane & 31, hl = lane >> 5;

    // group-per-XCD swizzle (see header comment)
    const int bid = blockIdx.x;
    const int xs = bid & 7, q = bid >> 3;
    const int mIdx = xs * 4 + (q & 3);
    const int nt   = q >> 2;

    const int mBase = mIdx * 128, nBase = nt * 32;
    const int8_t* wbStrip = WB + (size_t)nt * 24 * 12288;
    const int fragOff = wave * 4096 + lane * 16;

    float vmem[16], isyn[16];
#pragma unroll
    for (int r = 0; r < 16; ++r) { vmem[r] = 0.0f; isyn[r] = 0.0f; }

    int4v aA[4];

    // initial prestage: X(t=0) A(0) -> aA, B(0) -> sB0
    stage_b0(wbStrip, sB0, wave, lane);
    loadA(Xall + (size_t)mIdx * 16 * 16384 + fragOff, aA);

    for (int t = 0; t < T_STEPS; ++t) {
        int16v acc[3] = {};

        // ---- X phase: kt 0..15 (A(0)/B(0) prestaged by prior step's pre-epilogue) ----
        const int8_t* XtW = Xall + (size_t)t * ((size_t)B_DIM * I_DIM)
                          + (size_t)mIdx * 16 * 16384 + fragOff;
        run_phase<16>(XtW, wbStrip, sB0, sB1, aA, wave, lane, acc);

        // ---- recurrent phase: needs z(t-1) from the 32 blocks of this mIdx group ----
        if (t > 0) {
            const int8_t* zbChunk = wbStrip + (size_t)16 * 12288;
            // prestage z-phase B(0) into the freed sB0 (W independent of z)
            stage_b0(zbChunk, sB0, wave, lane);
            if (tid == 0) {
                const uint32_t* f = cnt + ((size_t)mIdx * 13 + (t - 1)) * 32;
                while (__hip_atomic_load((uint32_t*)f, __ATOMIC_RELAXED, __HIP_MEMORY_SCOPE_AGENT) < 32u)
                    __builtin_amdgcn_s_sleep(2);
            }
            __syncthreads();   // spin visible to all; full compiler barrier
            const int8_t* zW = ZS + (size_t)(t - 1) * ZBYTES + (size_t)mIdx * 8 * 16384 + fragOff;
            loadA(zW, aA);     // z-phase A(0); first iter's vmcnt(3) drains it
            run_phase<8>(zW, zbChunk, sB0, sB1, aA, wave, lane, acc);
        }

        // ---- prestage NEXT step's X-phase A(0)/B(0): in flight during the epilogue ----
        if (t + 1 < T_STEPS) {
            stage_b0(wbStrip, sB0, wave, lane);
            loadA(Xall + (size_t)(t + 1) * ((size_t)B_DIM * I_DIM)
                  + (size_t)mIdx * 16 * 16384 + fragOff, aA);
        }

        // ---- LIF epilogue (registers): C/D row=(r&3)+8*(r>>2)+4*hl, col=lane32 ----
#pragma unroll
        for (int r = 0; r < 16; ++r) {
#pragma clang fp contract(off)
            // exact digit combine (|counts| < 2^24)
            float cur = (float)acc[2][r] * (1.0f / 512.0f)
                      + (float)acc[1][r] * (1.0f / 131072.0f)
                      + (float)acc[0][r] * (1.0f / 33554432.0f);
            int row = (r & 3) + 8 * (r >> 2) + 4 * hl;    // 0..31 (C/D layout)
            float v_dec = vmem[r] + 0.1f * ((0.0f - vmem[r]) + isyn[r]);
            float i_dec = isyn[r] - 0.2f * isyn[r];
            bool z = (v_dec > 1.0f);
            vmem[r] = z ? 0.0f : v_dec;                   // == (1-z)*v_dec + z*V_RESET exactly
            isyn[r] = i_dec + cur;
            if (t == T_STEPS - 1) {
                int b = mBase + wave * 32 + row;
                int h = nBase + lane32;
                Zbf[(size_t)b * H_DIM + h] = z ? (uint16_t)0x3F80 : (uint16_t)0;
            } else {
                // [group=wave][kk=nt&3][lane'=(lane32>>4)*32+row][j=lane32&15] into sZ
                sZ[wave * 1024 + ((lane32 >> 4) * 32 + row) * 16 + (lane32 & 15)]
                    = z ? (int8_t)1 : (int8_t)0;
            }
        }

        if (t < T_STEPS - 1) {
            __syncthreads();   // sZ complete (also drains prestaged A/B for next X phase)
            // repack: 16 contiguous bytes/thread -> two 8B agent-scope stores
            const u64* sp = (const u64*)&sZ[tid * 16];
            u64 v0 = sp[0], v1 = sp[1];
            int8_t* dst = ZS + (size_t)t * ZBYTES + ((size_t)mIdx * 8 + (nt >> 2)) * 16384
                        + (tid >> 6) * 4096 + (nt & 3) * 1024 + (tid & 63) * 16;
            __hip_atomic_store((u64*)dst,       v0, __ATOMIC_RELAXED, __HIP_MEMORY_SCOPE_AGENT);
            __hip_atomic_store((u64*)(dst + 8), v1, __ATOMIC_RELAXED, __HIP_MEMORY_SCOPE_AGENT);
            __syncthreads();   // drains vmcnt(0): all z-stores acked at the coherence point
            if (tid == 0)
                __hip_atomic_fetch_add(&cnt[((size_t)mIdx * 13 + t) * 32], 1u,
                                       __ATOMIC_RELAXED, __HIP_MEMORY_SCOPE_AGENT);
        }
    }
}

// ---------- output GEMM: out = z_T @ out_w^T + out_b (bf16x3) ----------
__launch_bounds__(256)
__global__ void out_gemm_kernel(const uint16_t* __restrict__ Zfin,  // [B][H_DIM] bf16
                                const uint16_t* __restrict__ OW3,   // [3][O_DIM][H_DIM] bf16
                                const float* __restrict__ out_b,
                                float* __restrict__ out) {
    __shared__ uint16_t sA[16 * 32];        // 1 KB : [row(16)][k(32)]
    __shared__ uint16_t sB[3][128 * 32];    // 24 KB: [s][row(128)][k(32)]

    const int tid  = threadIdx.x;
    const int wave = tid >> 6, lane = tid & 63;
    const int quad = lane >> 4, col = lane & 15;

    const int mBase = blockIdx.x * 16;

    floatx4 acc[2] = {};

    const int ldRow = lane >> 2;        // 0..15
    const int ldCol = (lane & 3) * 8;   // element offset (x2B = 16B)

    for (int kt = 0; kt < H_DIM / 32; ++kt) {
        const int kb = kt * 32;
        __syncthreads();
        if (wave == 0) {
            const uint16_t* g = Zfin + (size_t)(mBase + ldRow) * H_DIM + kb + ldCol;
            gload_lds16(g, &sA[0]);
        }
#pragma unroll
        for (int s = 0; s < 3; ++s) {
            const uint16_t* wsrc = OW3 + (size_t)s * O_DIM * H_DIM;
#pragma unroll
            for (int j = 0; j < 2; ++j) {
                const int rseg = j * 4 + wave;   // 0..7, 16 rows each
                const uint16_t* g = wsrc + (size_t)(rseg * 16 + ldRow) * H_DIM + kb + ldCol;
                gload_lds16(g, &sB[s][rseg * 16 * 32]);
            }
        }
        __syncthreads();

        bf16x8 aF = *reinterpret_cast<const bf16x8*>(&sA[col * 32 + quad * 8]);
#pragma unroll
        for (int s = 0; s < 3; ++s) {
#pragma unroll
            for (int ni = 0; ni < 2; ++ni) {
                int row = wave * 32 + ni * 16 + col;
                bf16x8 bF = *reinterpret_cast<const bf16x8*>(&sB[s][row * 32 + quad * 8]);
                acc[ni] = __builtin_amdgcn_mfma_f32_16x16x32_bf16(aF, bF, acc[ni], 0, 0, 0);
            }
        }
    }

    {
#pragma clang fp contract(off)
#pragma unroll
        for (int ni = 0; ni < 2; ++ni)
#pragma unroll
            for (int r = 0; r < 4; ++r) {
                int b = mBase + quad * 4 + r;          // C/D: row = quad*4 + reg
                int h = wave * 32 + ni * 16 + col;     //      col = lane&15
                out[(size_t)b * O_DIM + h] = acc[ni][r] + out_b[h];
            }
    }
}

extern "C" void kernel_launch(void* const* d_in, const int* in_sizes, int n_in,
                              void* d_out, int out_size, void* d_ws, size_t ws_size,
                              hipStream_t stream) {
    const float* x     = (const float*)d_in[0];
    const float* w_in  = (const float*)d_in[1];
    const float* w_rec = (const float*)d_in[2];
    const float* out_w = (const float*)d_in[3];
    const float* out_b = (const float*)d_in[4];
    float* out = (float*)d_out;

    char* ws = (char*)d_ws;
    size_t off = 0;
    int8_t*   WB   = (int8_t*)(ws + off);   off += (size_t)3 * H_DIM * K_TOT;        // 9.4 MB
    uint16_t* OW3  = (uint16_t*)(ws + off); off += (size_t)3 * O_DIM * H_DIM * 2;    // 0.8 MB
    int8_t*   Xall = (int8_t*)(ws + off);   off += (size_t)T_STEPS * B_DIM * I_DIM;  // 117 MB
    uint16_t* Zbf  = (uint16_t*)(ws + off); off += (size_t)B_DIM * H_DIM * 2;        // 8 MB
    int8_t*   ZS   = (int8_t*)(ws + off);   off += (size_t)13 * ZBYTES;              // 54.5 MB (per-step z)
    uint32_t* CNT  = (uint32_t*)(ws + off); off += (size_t)32 * 13 * 32 * 4;         // 53 KB

    split_w_kernel<<<(H_DIM * K_TOT) / 256, 256, 0, stream>>>(w_in, w_rec, WB);
    split_ow_kernel<<<(O_DIM * H_DIM) / 256, 256, 0, stream>>>(out_w, OW3);
    cvt_x_kernel<<<(int)(((size_t)T_STEPS * B_DIM * I_DIM / 16) / 256), 256, 0, stream>>>(x, Xall);
    zero_cnt_kernel<<<(32 * 13 * 32) / 256, 256, 0, stream>>>(CNT);

    // PLAIN launch: capture-safe. Co-residency by exact-fit occupancy (see kernel comment).
    lif_persist_kernel<<<dim3(1024), dim3(256), 0, stream>>>(Xall, WB, ZS, Zbf, CNT);

    out_gemm_kernel<<<B_DIM / 16, 256, 0, stream>>>(Zbf, OW3, out_b, out);
}

// Round 9
// 1253.501 us; speedup vs baseline: 1.0814x; 1.0335x over previous
//
#include <hip/hip_runtime.h>
#include <stdint.h>

#define T_STEPS 14
#define B_DIM   4096
#define I_DIM   2048
#define H_DIM   1024
#define O_DIM   128
#define K_TOT   3072   // I_DIM + H_DIM
#define ZBYTES  ((size_t)B_DIM * H_DIM)

// fixed-point scale 2^25: |w|max ~0.16 -> |W| ~5.1M, 3 signed base-256 digits exact
#define WSCALE_F 33554432.0f

typedef __bf16  bf16x8  __attribute__((ext_vector_type(8)));
typedef float   floatx4 __attribute__((ext_vector_type(4)));
typedef int     int4v   __attribute__((ext_vector_type(4)));
typedef int     int16v  __attribute__((ext_vector_type(16)));
typedef unsigned long long u64;

__device__ __forceinline__ uint16_t f2bf_rne(float f) {
    uint32_t u = __float_as_uint(f);
    u += 0x7fffu + ((u >> 16) & 1u);
    return (uint16_t)(u >> 16);
}
__device__ __forceinline__ float bf2f(uint16_t h) {
    return __uint_as_float(((uint32_t)h) << 16);
}

// async global->LDS, 16B/lane; LDS dest = wave-uniform base + lane*16 (implicit)
__device__ __forceinline__ void gload_lds16(const void* g, void* l) {
    __builtin_amdgcn_global_load_lds((__attribute__((address_space(1))) void*)g,
                                     (__attribute__((address_space(3))) void*)l, 16, 0, 0);
}

// ================= fragment-order layouts, BK=128 (validated r11) =================
// B digits: WB[nt(32)][ktw(24)][s(3)][kk(4)][lane(64)][16B]      (12 KB chunks)
// A spikes: Xall[t][mIdx(32)][ktx(16)][group(4)][kk(4)][lane(64)][16B]  (16 KB chunks)
// Z state:  ZS[t][mIdx(32)][ktz(8)][group(4)][kk(4)][lane(64)][16B]     (16 KB chunks)
// element (row = group*32 + (lane&31), k = kt*128 + kk*32 + (lane>>5)*16 + j)

__global__ void split_w_kernel(const float* __restrict__ w_in, const float* __restrict__ w_rec,
                               int8_t* __restrict__ WB) {
    int idx = blockIdx.x * 256 + threadIdx.x;          // over H_DIM*K_TOT
    int h = idx / K_TOT;
    int k = idx - h * K_TOT;
    float w = (k < I_DIM) ? w_in[(size_t)h * I_DIM + k]
                          : w_rec[(size_t)h * H_DIM + (k - I_DIM)];
    int W  = __float2int_rn(w * WSCALE_F);
    int d0 = (int8_t)(W & 0xFF);
    int r1 = (W - d0) >> 8;
    int d1 = (int8_t)(r1 & 0xFF);
    int d2 = (r1 - d1) >> 8;                           // |d2| <= ~80
    int nt = h >> 5, n32 = h & 31;
    int ktw = k >> 7, k128 = k & 127;
    int kk = k128 >> 5, half = (k128 >> 4) & 1, j = k128 & 15;
    int lane = half * 32 + n32;
    size_t base = (size_t)(nt * 24 + ktw) * 12288 + kk * 1024 + lane * 16 + j;
    WB[base] = (int8_t)d0; WB[base + 4096] = (int8_t)d1; WB[base + 8192] = (int8_t)d2;
}

// ---------- out_w -> bf16 hi/mid/lo (validated) ----------
__global__ void split_ow_kernel(const float* __restrict__ out_w, uint16_t* __restrict__ OW3) {
    int idx = blockIdx.x * 256 + threadIdx.x;          // over O_DIM*H_DIM
    float w = out_w[idx];
    uint16_t hi = f2bf_rne(w);
    float r1 = w - bf2f(hi);
    uint16_t mid = f2bf_rne(r1);
    float r2 = r1 - bf2f(mid);
    uint16_t lo = f2bf_rne(r2);
    const size_t S = (size_t)O_DIM * H_DIM;
    OW3[idx] = hi; OW3[idx + S] = mid; OW3[idx + 2 * S] = lo;
}

// ---------- x fp32 -> i8, ALL timesteps, BK=128 fragment-order (validated r11) ----------
__global__ void cvt_x_kernel(const float* __restrict__ x, int8_t* __restrict__ xb) {
    size_t gid = (size_t)blockIdx.x * 256 + threadIdx.x;   // one 16B output granule each
    int g = (int)(gid & 1023);                             // granule within 16KB chunk
    size_t chunk = gid >> 10;                              // (t*32 + mIdx)*16 + kt
    int kt   = (int)(chunk & 15);
    int mIdx = (int)((chunk >> 4) & 31);
    int t    = (int)(chunk >> 9);
    int group = g >> 8, kk = (g >> 6) & 3, lane = g & 63;
    int half = lane >> 5, row32 = lane & 31;
    int b = mIdx * 128 + group * 32 + row32;
    int k = kt * 128 + kk * 32 + half * 16;
    const float4* src = (const float4*)(x + ((size_t)t * B_DIM + b) * I_DIM + k);
    union { int8_t bytes[16]; int4v v; } u;
#pragma unroll
    for (int q = 0; q < 4; ++q) {
        float4 f = src[q];
        u.bytes[q * 4 + 0] = (int8_t)(f.x > 0.5f);
        u.bytes[q * 4 + 1] = (int8_t)(f.y > 0.5f);
        u.bytes[q * 4 + 2] = (int8_t)(f.z > 0.5f);
        u.bytes[q * 4 + 3] = (int8_t)(f.w > 0.5f);
    }
    ((int4v*)xb)[gid] = u.v;
}

// ---------- zero the group-sync counters ----------
// agent-scope stores: zeros reach the coherence point regardless of replay history
__global__ void zero_cnt_kernel(uint32_t* __restrict__ cnt) {
    __hip_atomic_store(&cnt[blockIdx.x * 256 + threadIdx.x], 0u,
                       __ATOMIC_RELAXED, __HIP_MEMORY_SCOPE_AGENT);
}

// ============== R9: 128M x 64N tile — 2x arithmetic intensity per CU ==============
// R8 post-mortem: ~695us plateau invariant across 4 schedules; the invariant was
// per-CU ingress (112 KB per CU-iteration). This tile serves 24 MFMA/wave from
// 16KB A + 24KB B (two nt strips) per block-iter -> 80 KB/CU-iter at identical
// MFMA/CU-iter (-29% bytes). Pipeline identical to R8 (validated): B LDS ping-pong +
// in-place A prefetch; per iter issues 6 B-stages + 4 A-loads; vmcnt(6) drains
// A(kt)+B(kt), keeps B(kt+1):6 in flight across the barrier. Tail: vmcnt(0).
__device__ __forceinline__ void loadA(const int8_t* __restrict__ aP, int4v (&a)[4]) {
    a[0] = *(const int4v*)(aP);
    a[1] = *(const int4v*)(aP + 1024);
    a[2] = *(const int4v*)(aP + 2048);
    a[3] = *(const int4v*)(aP + 3072);
}

// stage both 12KB strips of one K-step into a 24KB LDS buffer (6 x 1KB per wave)
__device__ __forceinline__ void stage_b(const int8_t* __restrict__ bA,
                                        const int8_t* __restrict__ bB,
                                        int8_t* dst, int wave, int lane) {
    gload_lds16(bA + (size_t)wave * 1024 + lane * 16,       dst + wave * 1024);
    gload_lds16(bA + (size_t)(4 + wave) * 1024 + lane * 16, dst + (4 + wave) * 1024);
    gload_lds16(bA + (size_t)(8 + wave) * 1024 + lane * 16, dst + (8 + wave) * 1024);
    gload_lds16(bB + (size_t)wave * 1024 + lane * 16,       dst + 12288 + wave * 1024);
    gload_lds16(bB + (size_t)(4 + wave) * 1024 + lane * 16, dst + 12288 + (4 + wave) * 1024);
    gload_lds16(bB + (size_t)(8 + wave) * 1024 + lane * 16, dst + 12288 + (8 + wave) * 1024);
}

__device__ __forceinline__ void lif_iter(const int8_t* __restrict__ aPn,   // A(kt+1) per-thread or null
                                         const int8_t* __restrict__ bPnA,  // B(kt+1) strip0 or null
                                         const int8_t* __restrict__ bPnB,  // B(kt+1) strip1 or null
                                         const int8_t* cur, int8_t* nxt,   // 24KB LDS ping-pong
                                         int4v (&aA)[4],
                                         int wave, int lane, bool stage_next,
                                         int16v (&acc)[2][3]) {
    if (stage_next) {
        stage_b(bPnA, bPnB, nxt, wave, lane);
        __builtin_amdgcn_sched_barrier(0);
        asm volatile("s_waitcnt vmcnt(6)" ::: "memory");   // drain A(kt)+B(kt); keep B(kt+1):6
    } else {
        asm volatile("s_waitcnt vmcnt(0)" ::: "memory");   // tail: drain A(kt)+B(kt)
    }
    __builtin_amdgcn_s_barrier();                          // all waves' B(kt) landed
    __builtin_amdgcn_sched_barrier(0);
    __builtin_amdgcn_s_setprio(1);                         // T5: favor MFMA-entering wave
#pragma unroll
    for (int kk = 0; kk < 4; ++kk) {
#pragma unroll
        for (int n = 0; n < 2; ++n) {
#pragma unroll
            for (int s = 0; s < 3; ++s) {
                int4v bF = *(const int4v*)(cur + n * 12288 + s * 4096 + kk * 1024 + lane * 16);
                acc[n][s] = __builtin_amdgcn_mfma_i32_32x32x32_i8(aA[kk], bF, acc[n][s], 0, 0, 0);
            }
        }
    }
    __builtin_amdgcn_s_setprio(0);
    __builtin_amdgcn_sched_barrier(0);                     // pin A-issue AFTER its last reader
    if (aPn) loadA(aPn, aA);                               // A(kt+1) -> same regs (WAR-ordered)
    asm volatile("s_waitcnt lgkmcnt(0)" ::: "memory");     // reads of 'cur' done
    __builtin_amdgcn_s_barrier();                          // safe to overwrite 'cur' next iter
}

// Contract: caller has ISSUED A(0)->aA and B(0)->sB0 (first iter's vmcnt(6) or an
// intervening __syncthreads completes them). Starts cur=sB0, ends with sB0 free.
template<int NKT>
__device__ __forceinline__ void run_phase(const int8_t* __restrict__ aW,   // per-thread frag base, +kt*16384
                                          const int8_t* __restrict__ bA,   // strip0 base, +kt*12288
                                          const int8_t* __restrict__ bB,   // strip1 base, +kt*12288
                                          int8_t* sB0, int8_t* sB1,
                                          int4v (&aA)[4],
                                          int wave, int lane, int16v (&acc)[2][3]) {
#pragma unroll 1
    for (int kt = 0; kt + 2 < NKT; kt += 2) {
        lif_iter(aW + (size_t)(kt + 1) * 16384, bA + (size_t)(kt + 1) * 12288,
                 bB + (size_t)(kt + 1) * 12288, sB0, sB1, aA, wave, lane, true, acc);
        lif_iter(aW + (size_t)(kt + 2) * 16384, bA + (size_t)(kt + 2) * 12288,
                 bB + (size_t)(kt + 2) * 12288, sB1, sB0, aA, wave, lane, true, acc);
    }
    lif_iter(aW + (size_t)(NKT - 1) * 16384, bA + (size_t)(NKT - 1) * 12288,
             bB + (size_t)(NKT - 1) * 12288, sB0, sB1, aA, wave, lane, true, acc);
    lif_iter(nullptr, nullptr, nullptr, sB1, sB0, aA, wave, lane, false, acc);
}

// ================= persistent LIF: all 14 steps, ONE PLAIN launch =================
// Tile 128M x 64N, grid 512, 2 blocks/CU exact fit: LDS 56KB x2 = 112KB <= 160KB,
// VGPR <= 256 (launch_bounds 256,2 -> 8 waves/CU), 8 waves <= 32. 512 = 2 x 256 CU.
// mIdx group = 16 blocks (flag target 16). XCD grouping: mIdx = (bid&7)*4 + (q&3),
// nt2 = q>>2 — group's X chunk fetched by one XCD.
// Coherence protocol — validated R6/R8 through the timed path (no per-step fence):
//  - dispatch boundaries invalidate L2s (replay staleness handled);
//  - ZS[t] virgin until producers' agent-scope 8B stores (LLC write-through,
//    vmcnt-acked before flag add); consumers spin + __syncthreads -> plain cached loads;
//  - flag spin: relaxed agent-scope loads (no invalidates, groups drift freely).
__launch_bounds__(256, 2)
__global__ void lif_persist_kernel(const int8_t* __restrict__ Xall,
                                   const int8_t* __restrict__ WB,
                                   int8_t* __restrict__ ZS,      // 13 per-step z buffers
                                   uint16_t* __restrict__ Zbf,
                                   uint32_t* __restrict__ cnt) {
    __shared__ int8_t sB0[24576];   // [strip(2)][s(3)][kk(4)][lane(64)][16B]
    __shared__ int8_t sB1[24576];
    __shared__ int8_t sZ[8192];     // [strip(2)][wave(4)][1024] z repack staging

    const int tid  = threadIdx.x;
    const int wave = tid >> 6, lane = tid & 63;
    const int lane32 = lane & 31, hl = lane >> 5;

    // group-per-XCD swizzle: 512 blocks, 64 per XCD = 4 mIdx x 16 nt2
    const int bid = blockIdx.x;
    const int xs = bid & 7, q = bid >> 3;       // q in 0..63
    const int mIdx = xs * 4 + (q & 3);
    const int nt2  = q >> 2;                    // 0..15, covers nt = 2*nt2, 2*nt2+1

    const int mBase = mIdx * 128, nBase = nt2 * 64;
    const int8_t* wbA = WB + (size_t)(2 * nt2) * 24 * 12288;
    const int8_t* wbB = WB + (size_t)(2 * nt2 + 1) * 24 * 12288;
    const int fragOff = wave * 4096 + lane * 16;

    float vmem[2][16], isyn[2][16];
#pragma unroll
    for (int n = 0; n < 2; ++n)
#pragma unroll
        for (int r = 0; r < 16; ++r) { vmem[n][r] = 0.0f; isyn[n][r] = 0.0f; }

    int4v aA[4];

    // initial prestage: X(t=0) A(0) -> aA, B(0) both strips -> sB0
    stage_b(wbA, wbB, sB0, wave, lane);
    loadA(Xall + (size_t)mIdx * 16 * 16384 + fragOff, aA);

    for (int t = 0; t < T_STEPS; ++t) {
        int16v acc[2][3] = {};

        // ---- X phase: kt 0..15 (A(0)/B(0) prestaged) ----
        const int8_t* XtW = Xall + (size_t)t * ((size_t)B_DIM * I_DIM)
                          + (size_t)mIdx * 16 * 16384 + fragOff;
        run_phase<16>(XtW, wbA, wbB, sB0, sB1, aA, wave, lane, acc);

        // ---- recurrent phase: needs z(t-1) from the 16 blocks of this mIdx group ----
        if (t > 0) {
            const int8_t* zbA = wbA + (size_t)16 * 12288;
            const int8_t* zbB = wbB + (size_t)16 * 12288;
            stage_b(zbA, zbB, sB0, wave, lane);   // prestage z-phase B(0) (independent of z)
            if (tid == 0) {
                const uint32_t* f = cnt + ((size_t)mIdx * 13 + (t - 1)) * 32;
                while (__hip_atomic_load((uint32_t*)f, __ATOMIC_RELAXED, __HIP_MEMORY_SCOPE_AGENT) < 16u)
                    __builtin_amdgcn_s_sleep(2);
            }
            __syncthreads();   // spin visible to all; full compiler barrier
            const int8_t* zW = ZS + (size_t)(t - 1) * ZBYTES + (size_t)mIdx * 8 * 16384 + fragOff;
            loadA(zW, aA);     // z-phase A(0); first iter's vmcnt(6) drains it
            run_phase<8>(zW, zbA, zbB, sB0, sB1, aA, wave, lane, acc);
        }

        // ---- prestage NEXT step's X-phase A(0)/B(0): in flight during the epilogue ----
        if (t + 1 < T_STEPS) {
            stage_b(wbA, wbB, sB0, wave, lane);
            loadA(Xall + (size_t)(t + 1) * ((size_t)B_DIM * I_DIM)
                  + (size_t)mIdx * 16 * 16384 + fragOff, aA);
        }

        // ---- LIF epilogue (registers): C/D row=(r&3)+8*(r>>2)+4*hl, col=lane32 ----
#pragma unroll
        for (int n = 0; n < 2; ++n) {
#pragma unroll
            for (int r = 0; r < 16; ++r) {
#pragma clang fp contract(off)
                // exact digit combine (|counts| < 2^24)
                float cur = (float)acc[n][2][r] * (1.0f / 512.0f)
                          + (float)acc[n][1][r] * (1.0f / 131072.0f)
                          + (float)acc[n][0][r] * (1.0f / 33554432.0f);
                int row = (r & 3) + 8 * (r >> 2) + 4 * hl;    // 0..31 (C/D layout)
                float v_dec = vmem[n][r] + 0.1f * ((0.0f - vmem[n][r]) + isyn[n][r]);
                float i_dec = isyn[n][r] - 0.2f * isyn[n][r];
                bool z = (v_dec > 1.0f);
                vmem[n][r] = z ? 0.0f : v_dec;                // == (1-z)*v_dec + z*V_RESET exactly
                isyn[n][r] = i_dec + cur;
                if (t == T_STEPS - 1) {
                    int b = mBase + wave * 32 + row;
                    int h = nBase + n * 32 + lane32;
                    Zbf[(size_t)b * H_DIM + h] = z ? (uint16_t)0x3F80 : (uint16_t)0;
                } else {
                    // strip-local fragment order into sZ
                    sZ[n * 4096 + wave * 1024 + ((lane32 >> 4) * 32 + row) * 16 + (lane32 & 15)]
                        = z ? (int8_t)1 : (int8_t)0;
                }
            }
        }

        if (t < T_STEPS - 1) {
            __syncthreads();   // sZ complete (also drains prestaged A/B for next X phase)
            // repack: per strip, 16 contiguous bytes/thread -> two 8B agent-scope stores
#pragma unroll
            for (int n = 0; n < 2; ++n) {
                const u64* sp = (const u64*)&sZ[n * 4096 + tid * 16];
                u64 v0 = sp[0], v1 = sp[1];
                const int ntn = nt2 * 2 + n;
                int8_t* dst = ZS + (size_t)t * ZBYTES + ((size_t)mIdx * 8 + (ntn >> 2)) * 16384
                            + (tid >> 6) * 4096 + (ntn & 3) * 1024 + (tid & 63) * 16;
                __hip_atomic_store((u64*)dst,       v0, __ATOMIC_RELAXED, __HIP_MEMORY_SCOPE_AGENT);
                __hip_atomic_store((u64*)(dst + 8), v1, __ATOMIC_RELAXED, __HIP_MEMORY_SCOPE_AGENT);
            }
            __syncthreads();   // drains vmcnt(0): all z-stores acked at the coherence point
            if (tid == 0)
                __hip_atomic_fetch_add(&cnt[((size_t)mIdx * 13 + t) * 32], 1u,
                                       __ATOMIC_RELAXED, __HIP_MEMORY_SCOPE_AGENT);
        }
    }
}

// ---------- output GEMM: out = z_T @ out_w^T + out_b (bf16x3) ----------
__launch_bounds__(256)
__global__ void out_gemm_kernel(const uint16_t* __restrict__ Zfin,  // [B][H_DIM] bf16
                                const uint16_t* __restrict__ OW3,   // [3][O_DIM][H_DIM] bf16
                                const float* __restrict__ out_b,
                                float* __restrict__ out) {
    __shared__ uint16_t sA[16 * 32];        // 1 KB : [row(16)][k(32)]
    __shared__ uint16_t sB[3][128 * 32];    // 24 KB: [s][row(128)][k(32)]

    const int tid  = threadIdx.x;
    const int wave = tid >> 6, lane = tid & 63;
    const int quad = lane >> 4, col = lane & 15;

    const int mBase = blockIdx.x * 16;

    floatx4 acc[2] = {};

    const int ldRow = lane >> 2;        // 0..15
    const int ldCol = (lane & 3) * 8;   // element offset (x2B = 16B)

    for (int kt = 0; kt < H_DIM / 32; ++kt) {
        const int kb = kt * 32;
        __syncthreads();
        if (wave == 0) {
            const uint16_t* g = Zfin + (size_t)(mBase + ldRow) * H_DIM + kb + ldCol;
            gload_lds16(g, &sA[0]);
        }
#pragma unroll
        for (int s = 0; s < 3; ++s) {
            const uint16_t* wsrc = OW3 + (size_t)s * O_DIM * H_DIM;
#pragma unroll
            for (int j = 0; j < 2; ++j) {
                const int rseg = j * 4 + wave;   // 0..7, 16 rows each
                const uint16_t* g = wsrc + (size_t)(rseg * 16 + ldRow) * H_DIM + kb + ldCol;
                gload_lds16(g, &sB[s][rseg * 16 * 32]);
            }
        }
        __syncthreads();

        bf16x8 aF = *reinterpret_cast<const bf16x8*>(&sA[col * 32 + quad * 8]);
#pragma unroll
        for (int s = 0; s < 3; ++s) {
#pragma unroll
            for (int ni = 0; ni < 2; ++ni) {
                int row = wave * 32 + ni * 16 + col;
                bf16x8 bF = *reinterpret_cast<const bf16x8*>(&sB[s][row * 32 + quad * 8]);
                acc[ni] = __builtin_amdgcn_mfma_f32_16x16x32_bf16(aF, bF, acc[ni], 0, 0, 0);
            }
        }
    }

    {
#pragma clang fp contract(off)
#pragma unroll
        for (int ni = 0; ni < 2; ++ni)
#pragma unroll
            for (int r = 0; r < 4; ++r) {
                int b = mBase + quad * 4 + r;          // C/D: row = quad*4 + reg
                int h = wave * 32 + ni * 16 + col;     //      col = lane&15
                out[(size_t)b * O_DIM + h] = acc[ni][r] + out_b[h];
            }
    }
}

extern "C" void kernel_launch(void* const* d_in, const int* in_sizes, int n_in,
                              void* d_out, int out_size, void* d_ws, size_t ws_size,
                              hipStream_t stream) {
    const float* x     = (const float*)d_in[0];
    const float* w_in  = (const float*)d_in[1];
    const float* w_rec = (const float*)d_in[2];
    const float* out_w = (const float*)d_in[3];
    const float* out_b = (const float*)d_in[4];
    float* out = (float*)d_out;

    char* ws = (char*)d_ws;
    size_t off = 0;
    int8_t*   WB   = (int8_t*)(ws + off);   off += (size_t)3 * H_DIM * K_TOT;        // 9.4 MB
    uint16_t* OW3  = (uint16_t*)(ws + off); off += (size_t)3 * O_DIM * H_DIM * 2;    // 0.8 MB
    int8_t*   Xall = (int8_t*)(ws + off);   off += (size_t)T_STEPS * B_DIM * I_DIM;  // 117 MB
    uint16_t* Zbf  = (uint16_t*)(ws + off); off += (size_t)B_DIM * H_DIM * 2;        // 8 MB
    int8_t*   ZS   = (int8_t*)(ws + off);   off += (size_t)13 * ZBYTES;              // 54.5 MB (per-step z)
    uint32_t* CNT  = (uint32_t*)(ws + off); off += (size_t)32 * 13 * 32 * 4;         // 53 KB

    split_w_kernel<<<(H_DIM * K_TOT) / 256, 256, 0, stream>>>(w_in, w_rec, WB);
    split_ow_kernel<<<(O_DIM * H_DIM) / 256, 256, 0, stream>>>(out_w, OW3);
    cvt_x_kernel<<<(int)(((size_t)T_STEPS * B_DIM * I_DIM / 16) / 256), 256, 0, stream>>>(x, Xall);
    zero_cnt_kernel<<<(32 * 13 * 32) / 256, 256, 0, stream>>>(CNT);

    // PLAIN launch: capture-safe. 512 blocks = 2/CU exact-fit (see kernel comment).
    lif_persist_kernel<<<dim3(512), dim3(256), 0, stream>>>(Xall, WB, ZS, Zbf, CNT);

    out_gemm_kernel<<<B_DIM / 16, 256, 0, stream>>>(Zbf, OW3, out_b, out);
}

// Round 10
// 1212.558 us; speedup vs baseline: 1.1179x; 1.0338x over previous
//
#include <hip/hip_runtime.h>
#include <stdint.h>

#define T_STEPS 14
#define B_DIM   4096
#define I_DIM   2048
#define H_DIM   1024
#define O_DIM   128
#define K_TOT   3072   // I_DIM + H_DIM
#define ZBYTES  ((size_t)B_DIM * H_DIM)

// fixed-point scale 2^25: |w|max ~0.16 -> |W| ~5.1M, 3 signed base-256 digits exact
#define WSCALE_F 33554432.0f

typedef __bf16  bf16x8  __attribute__((ext_vector_type(8)));
typedef float   floatx4 __attribute__((ext_vector_type(4)));
typedef int     int4v   __attribute__((ext_vector_type(4)));
typedef int     int16v  __attribute__((ext_vector_type(16)));
typedef unsigned long long u64;

__device__ __forceinline__ uint16_t f2bf_rne(float f) {
    uint32_t u = __float_as_uint(f);
    u += 0x7fffu + ((u >> 16) & 1u);
    return (uint16_t)(u >> 16);
}
__device__ __forceinline__ float bf2f(uint16_t h) {
    return __uint_as_float(((uint32_t)h) << 16);
}

// async global->LDS, 16B/lane; LDS dest = wave-uniform base + lane*16 (implicit)
__device__ __forceinline__ void gload_lds16(const void* g, void* l) {
    __builtin_amdgcn_global_load_lds((__attribute__((address_space(1))) void*)g,
                                     (__attribute__((address_space(3))) void*)l, 16, 0, 0);
}

// ================= fragment-order layouts, BK=128 (validated r11) =================
// B digits: WB[nt(32)][ktw(24)][s(3)][kk(4)][lane(64)][16B]      (12 KB chunks)
// A spikes: Xall[t][mIdx(32)][ktx(16)][group(4)][kk(4)][lane(64)][16B]  (16 KB chunks)
// Z state:  ZS[t][mIdx(32)][ktz(8)][group(4)][kk(4)][lane(64)][16B]     (16 KB chunks)
// element (row = group*32 + (lane&31), k = kt*128 + kk*32 + (lane>>5)*16 + j)

__global__ void split_w_kernel(const float* __restrict__ w_in, const float* __restrict__ w_rec,
                               int8_t* __restrict__ WB) {
    int idx = blockIdx.x * 256 + threadIdx.x;          // over H_DIM*K_TOT
    int h = idx / K_TOT;
    int k = idx - h * K_TOT;
    float w = (k < I_DIM) ? w_in[(size_t)h * I_DIM + k]
                          : w_rec[(size_t)h * H_DIM + (k - I_DIM)];
    int W  = __float2int_rn(w * WSCALE_F);
    int d0 = (int8_t)(W & 0xFF);
    int r1 = (W - d0) >> 8;
    int d1 = (int8_t)(r1 & 0xFF);
    int d2 = (r1 - d1) >> 8;                           // |d2| <= ~80
    int nt = h >> 5, n32 = h & 31;
    int ktw = k >> 7, k128 = k & 127;
    int kk = k128 >> 5, half = (k128 >> 4) & 1, j = k128 & 15;
    int lane = half * 32 + n32;
    size_t base = (size_t)(nt * 24 + ktw) * 12288 + kk * 1024 + lane * 16 + j;
    WB[base] = (int8_t)d0; WB[base + 4096] = (int8_t)d1; WB[base + 8192] = (int8_t)d2;
}

// ---------- out_w -> bf16 hi/mid/lo (validated) ----------
__global__ void split_ow_kernel(const float* __restrict__ out_w, uint16_t* __restrict__ OW3) {
    int idx = blockIdx.x * 256 + threadIdx.x;          // over O_DIM*H_DIM
    float w = out_w[idx];
    uint16_t hi = f2bf_rne(w);
    float r1 = w - bf2f(hi);
    uint16_t mid = f2bf_rne(r1);
    float r2 = r1 - bf2f(mid);
    uint16_t lo = f2bf_rne(r2);
    const size_t S = (size_t)O_DIM * H_DIM;
    OW3[idx] = hi; OW3[idx + S] = mid; OW3[idx + 2 * S] = lo;
}

// ---------- x fp32 -> i8, ALL timesteps, BK=128 fragment-order (validated r11) ----------
__global__ void cvt_x_kernel(const float* __restrict__ x, int8_t* __restrict__ xb) {
    size_t gid = (size_t)blockIdx.x * 256 + threadIdx.x;   // one 16B output granule each
    int g = (int)(gid & 1023);                             // granule within 16KB chunk
    size_t chunk = gid >> 10;                              // (t*32 + mIdx)*16 + kt
    int kt   = (int)(chunk & 15);
    int mIdx = (int)((chunk >> 4) & 31);
    int t    = (int)(chunk >> 9);
    int group = g >> 8, kk = (g >> 6) & 3, lane = g & 63;
    int half = lane >> 5, row32 = lane & 31;
    int b = mIdx * 128 + group * 32 + row32;
    int k = kt * 128 + kk * 32 + half * 16;
    const float4* src = (const float4*)(x + ((size_t)t * B_DIM + b) * I_DIM + k);
    union { int8_t bytes[16]; int4v v; } u;
#pragma unroll
    for (int q = 0; q < 4; ++q) {
        float4 f = src[q];
        u.bytes[q * 4 + 0] = (int8_t)(f.x > 0.5f);
        u.bytes[q * 4 + 1] = (int8_t)(f.y > 0.5f);
        u.bytes[q * 4 + 2] = (int8_t)(f.z > 0.5f);
        u.bytes[q * 4 + 3] = (int8_t)(f.w > 0.5f);
    }
    ((int4v*)xb)[gid] = u.v;
}

// ---------- zero the group-sync counters ----------
__global__ void zero_cnt_kernel(uint32_t* __restrict__ cnt) {
    __hip_atomic_store(&cnt[blockIdx.x * 256 + threadIdx.x], 0u,
                       __ATOMIC_RELAXED, __HIP_MEMORY_SCOPE_AGENT);
}

// ====== R10: BOTH operands staged global->LDS one FULL iteration ahead ======
// R9 post-mortem: every prior schedule exposed one A-load latency (HBM ~900cy) per
// iteration — R8/R9's in-place reg prefetch has only a ~50cy hiding window (issued
// after MFMA, drained at next iter's top); R7's 2nd reg buffer spilled. Fix: A goes
// through LDS like B. Per iter: 10 gload_lds (4 A-segs + 6 B-segs) for kt+1 ->
// vmcnt(10) drains the PREVIOUS iter's 10 (a full iteration ~2400cy > 900cy HBM),
// keeps this iter's 10 in flight across the barrier. A fragments then come from LDS
// via 4x ds_read_b128 (~120cy, hidden under the MFMA pipeline ramp).
// LDS: A ping-pong 32KB + B ping-pong 48KB = 81920 B/block; x2 blocks = 163840 =
// exactly the 160KiB pool. sZ aliases sA1 (dead at epilogue; orderings audited).
__device__ __forceinline__ void stage_a(const int8_t* __restrict__ aC, int8_t* dst,
                                        int wave, int lane) {
#pragma unroll
    for (int j = 0; j < 4; ++j) {
        const int seg = j * 4 + wave;
        gload_lds16(aC + (size_t)seg * 1024 + lane * 16, dst + seg * 1024);
    }
}
__device__ __forceinline__ void stage_b(const int8_t* __restrict__ bA,
                                        const int8_t* __restrict__ bB,
                                        int8_t* dst, int wave, int lane) {
    gload_lds16(bA + (size_t)wave * 1024 + lane * 16,       dst + wave * 1024);
    gload_lds16(bA + (size_t)(4 + wave) * 1024 + lane * 16, dst + (4 + wave) * 1024);
    gload_lds16(bA + (size_t)(8 + wave) * 1024 + lane * 16, dst + (8 + wave) * 1024);
    gload_lds16(bB + (size_t)wave * 1024 + lane * 16,       dst + 12288 + wave * 1024);
    gload_lds16(bB + (size_t)(4 + wave) * 1024 + lane * 16, dst + 12288 + (4 + wave) * 1024);
    gload_lds16(bB + (size_t)(8 + wave) * 1024 + lane * 16, dst + 12288 + (8 + wave) * 1024);
}

__device__ __forceinline__ void lif_iter(const int8_t* __restrict__ aCn,   // A(kt+1) chunk or null
                                         const int8_t* __restrict__ bAn,   // B(kt+1) strip0 or null
                                         const int8_t* __restrict__ bBn,   // B(kt+1) strip1 or null
                                         const int8_t* curA, const int8_t* curB,
                                         int8_t* nxtA, int8_t* nxtB,
                                         int wave, int lane, bool stage_next,
                                         int16v (&acc)[2][3]) {
    if (stage_next) {
        stage_a(aCn, nxtA, wave, lane);
        stage_b(bAn, bBn, nxtB, wave, lane);
        __builtin_amdgcn_sched_barrier(0);
        asm volatile("s_waitcnt vmcnt(10)" ::: "memory");  // drain A(kt)+B(kt) stages; keep kt+1's 10
    } else {
        asm volatile("s_waitcnt vmcnt(0)" ::: "memory");   // tail: drain everything
    }
    __builtin_amdgcn_s_barrier();                          // all waves' A(kt)/B(kt) landed
    __builtin_amdgcn_sched_barrier(0);
    // A fragments from LDS (latency hides under MFMA pipeline ramp)
    int4v aF[4];
#pragma unroll
    for (int kk = 0; kk < 4; ++kk)
        aF[kk] = *(const int4v*)(curA + wave * 4096 + kk * 1024 + lane * 16);
    __builtin_amdgcn_s_setprio(1);                         // T5: favor MFMA-entering wave
#pragma unroll
    for (int kk = 0; kk < 4; ++kk) {
#pragma unroll
        for (int n = 0; n < 2; ++n) {
#pragma unroll
            for (int s = 0; s < 3; ++s) {
                int4v bF = *(const int4v*)(curB + n * 12288 + s * 4096 + kk * 1024 + lane * 16);
                acc[n][s] = __builtin_amdgcn_mfma_i32_32x32x32_i8(aF[kk], bF, acc[n][s], 0, 0, 0);
            }
        }
    }
    __builtin_amdgcn_s_setprio(0);
    asm volatile("s_waitcnt lgkmcnt(0)" ::: "memory");     // reads of cur done
    __builtin_amdgcn_s_barrier();                          // safe to overwrite cur next iter
}

// Contract: caller has ISSUED A(0)->sA0 and B(0)->sB0 (first iter's vmcnt(10) or an
// intervening __syncthreads completes them). NKT even: phase starts at buf0, last
// compute uses buf1, leaves buf0 free for the next phase's prologue.
template<int NKT>
__device__ __forceinline__ void run_phase(const int8_t* __restrict__ aC,   // A chunk base, +kt*16384
                                          const int8_t* __restrict__ bA,   // strip0 base, +kt*12288
                                          const int8_t* __restrict__ bB,   // strip1 base, +kt*12288
                                          int8_t* sA0, int8_t* sA1, int8_t* sB0, int8_t* sB1,
                                          int wave, int lane, int16v (&acc)[2][3]) {
#pragma unroll 1
    for (int kt = 0; kt + 2 < NKT; kt += 2) {
        lif_iter(aC + (size_t)(kt + 1) * 16384, bA + (size_t)(kt + 1) * 12288,
                 bB + (size_t)(kt + 1) * 12288, sA0, sB0, sA1, sB1, wave, lane, true, acc);
        lif_iter(aC + (size_t)(kt + 2) * 16384, bA + (size_t)(kt + 2) * 12288,
                 bB + (size_t)(kt + 2) * 12288, sA1, sB1, sA0, sB0, wave, lane, true, acc);
    }
    lif_iter(aC + (size_t)(NKT - 1) * 16384, bA + (size_t)(NKT - 1) * 12288,
             bB + (size_t)(NKT - 1) * 12288, sA0, sB0, sA1, sB1, wave, lane, true, acc);
    lif_iter(nullptr, nullptr, nullptr, sA1, sB1, sA0, sB0, wave, lane, false, acc);
}

// ================= persistent LIF: all 14 steps, ONE PLAIN launch =================
// Tile 128M x 64N, grid 512, 2 blocks/CU: LDS 80KB x2 = 160KB exact, VGPR <= 256
// (launch_bounds 256,2 -> 8 waves/CU). mIdx group = 16 blocks (flag target 16).
// XCD grouping: mIdx = (bid&7)*4 + (q&3), nt2 = q>>2.
// Coherence protocol — validated R6/R8/R9 through the timed path (no per-step fence):
//  - dispatch boundaries invalidate L2s (replay staleness handled);
//  - ZS[t] virgin until producers' agent-scope 8B stores (LLC write-through,
//    vmcnt-acked before flag add); consumers spin + __syncthreads -> cached loads fresh;
//  - flag spin: relaxed agent-scope loads (no invalidates, groups drift freely).
__launch_bounds__(256, 2)
__global__ void lif_persist_kernel(const int8_t* __restrict__ Xall,
                                   const int8_t* __restrict__ WB,
                                   int8_t* __restrict__ ZS,      // 13 per-step z buffers
                                   uint16_t* __restrict__ Zbf,
                                   uint32_t* __restrict__ cnt) {
    __shared__ int8_t sMem[81920];
    int8_t* const sA0 = sMem;               // 16 KB
    int8_t* const sA1 = sMem + 16384;       // 16 KB (sZ aliases here during epilogue)
    int8_t* const sB0 = sMem + 32768;       // 24 KB
    int8_t* const sB1 = sMem + 57344;       // 24 KB
    int8_t* const sZ  = sA1;                // dead at epilogue time (see ordering notes)

    const int tid  = threadIdx.x;
    const int wave = tid >> 6, lane = tid & 63;
    const int lane32 = lane & 31, hl = lane >> 5;

    // group-per-XCD swizzle: 512 blocks, 64 per XCD = 4 mIdx x 16 nt2
    const int bid = blockIdx.x;
    const int xs = bid & 7, q = bid >> 3;       // q in 0..63
    const int mIdx = xs * 4 + (q & 3);
    const int nt2  = q >> 2;                    // 0..15, covers nt = 2*nt2, 2*nt2+1

    const int mBase = mIdx * 128, nBase = nt2 * 64;
    const int8_t* wbA = WB + (size_t)(2 * nt2) * 24 * 12288;
    const int8_t* wbB = WB + (size_t)(2 * nt2 + 1) * 24 * 12288;

    float vmem[2][16], isyn[2][16];
#pragma unroll
    for (int n = 0; n < 2; ++n)
#pragma unroll
        for (int r = 0; r < 16; ++r) { vmem[n][r] = 0.0f; isyn[n][r] = 0.0f; }

    // initial prologue: X(t=0) A(0) + B(0) -> buf0 (first iter's vmcnt(10) drains)
    stage_a(Xall + (size_t)mIdx * 16 * 16384, sA0, wave, lane);
    stage_b(wbA, wbB, sB0, wave, lane);

    for (int t = 0; t < T_STEPS; ++t) {
        int16v acc[2][3] = {};

        // ---- X phase: kt 0..15 (A(0)/B(0) already staged into buf0) ----
        const int8_t* XtC = Xall + (size_t)t * ((size_t)B_DIM * I_DIM)
                          + (size_t)mIdx * 16 * 16384;
        run_phase<16>(XtC, wbA, wbB, sA0, sA1, sB0, sB1, wave, lane, acc);

        // ---- recurrent phase: needs z(t-1) from the 16 blocks of this mIdx group ----
        if (t > 0) {
            const int8_t* zbA = wbA + (size_t)16 * 12288;
            const int8_t* zbB = wbB + (size_t)16 * 12288;
            stage_b(zbA, zbB, sB0, wave, lane);   // W independent of z: hide under spin
            if (tid == 0) {
                const uint32_t* f = cnt + ((size_t)mIdx * 13 + (t - 1)) * 32;
                while (__hip_atomic_load((uint32_t*)f, __ATOMIC_RELAXED, __HIP_MEMORY_SCOPE_AGENT) < 16u)
                    __builtin_amdgcn_s_sleep(2);
            }
            __syncthreads();   // spin visible; full barrier; drains B(0) stage
            const int8_t* zC = ZS + (size_t)(t - 1) * ZBYTES + (size_t)mIdx * 8 * 16384;
            stage_a(zC, sA0, wave, lane);         // z A(0); first iter's vmcnt(10) drains it
            run_phase<8>(zC, zbA, zbB, sA0, sA1, sB0, sB1, wave, lane, acc);
        }

        // ---- prestage NEXT step's X A(0)/B(0) into buf0 (free after even-NKT phase);
        //      latency hides under the epilogue; drained by epilogue __syncthreads ----
        if (t + 1 < T_STEPS) {
            stage_a(Xall + (size_t)(t + 1) * ((size_t)B_DIM * I_DIM)
                    + (size_t)mIdx * 16 * 16384, sA0, wave, lane);
            stage_b(wbA, wbB, sB0, wave, lane);
        }

        // ---- LIF epilogue (registers): C/D row=(r&3)+8*(r>>2)+4*hl, col=lane32 ----
#pragma unroll
        for (int n = 0; n < 2; ++n) {
#pragma unroll
            for (int r = 0; r < 16; ++r) {
#pragma clang fp contract(off)
                // exact digit combine (|counts| < 2^24)
                float cur = (float)acc[n][2][r] * (1.0f / 512.0f)
                          + (float)acc[n][1][r] * (1.0f / 131072.0f)
                          + (float)acc[n][0][r] * (1.0f / 33554432.0f);
                int row = (r & 3) + 8 * (r >> 2) + 4 * hl;    // 0..31 (C/D layout)
                float v_dec = vmem[n][r] + 0.1f * ((0.0f - vmem[n][r]) + isyn[n][r]);
                float i_dec = isyn[n][r] - 0.2f * isyn[n][r];
                bool z = (v_dec > 1.0f);
                vmem[n][r] = z ? 0.0f : v_dec;                // == (1-z)*v_dec + z*V_RESET exactly
                isyn[n][r] = i_dec + cur;
                if (t == T_STEPS - 1) {
                    int b = mBase + wave * 32 + row;
                    int h = nBase + n * 32 + lane32;
                    Zbf[(size_t)b * H_DIM + h] = z ? (uint16_t)0x3F80 : (uint16_t)0;
                } else {
                    // strip-local fragment order into sZ (aliases sA1 — dead here:
                    // last compute read sA1 before the phase's closing barrier)
                    sZ[n * 4096 + wave * 1024 + ((lane32 >> 4) * 32 + row) * 16 + (lane32 & 15)]
                        = z ? (int8_t)1 : (int8_t)0;
                }
            }
        }

        if (t < T_STEPS - 1) {
            __syncthreads();   // sZ complete; drains prestaged A/B (vmcnt 0)
            // repack: per strip, 16 contiguous bytes/thread -> two 8B agent-scope stores
#pragma unroll
            for (int n = 0; n < 2; ++n) {
                const u64* sp = (const u64*)&sZ[n * 4096 + tid * 16];
                u64 v0 = sp[0], v1 = sp[1];
                const int ntn = nt2 * 2 + n;
                int8_t* dst = ZS + (size_t)t * ZBYTES + ((size_t)mIdx * 8 + (ntn >> 2)) * 16384
                            + (tid >> 6) * 4096 + (ntn & 3) * 1024 + (tid & 63) * 16;
                __hip_atomic_store((u64*)dst,       v0, __ATOMIC_RELAXED, __HIP_MEMORY_SCOPE_AGENT);
                __hip_atomic_store((u64*)(dst + 8), v1, __ATOMIC_RELAXED, __HIP_MEMORY_SCOPE_AGENT);
            }
            __syncthreads();   // all z-stores acked at the coherence point; sZ reads done
            if (tid == 0)
                __hip_atomic_fetch_add(&cnt[((size_t)mIdx * 13 + t) * 32], 1u,
                                       __ATOMIC_RELAXED, __HIP_MEMORY_SCOPE_AGENT);
        }
    }
}

// ---------- output GEMM: out = z_T @ out_w^T + out_b (bf16x3) ----------
__launch_bounds__(256)
__global__ void out_gemm_kernel(const uint16_t* __restrict__ Zfin,  // [B][H_DIM] bf16
                                const uint16_t* __restrict__ OW3,   // [3][O_DIM][H_DIM] bf16
                                const float* __restrict__ out_b,
                                float* __restrict__ out) {
    __shared__ uint16_t sA[16 * 32];        // 1 KB : [row(16)][k(32)]
    __shared__ uint16_t sB[3][128 * 32];    // 24 KB: [s][row(128)][k(32)]

    const int tid  = threadIdx.x;
    const int wave = tid >> 6, lane = tid & 63;
    const int quad = lane >> 4, col = lane & 15;

    const int mBase = blockIdx.x * 16;

    floatx4 acc[2] = {};

    const int ldRow = lane >> 2;        // 0..15
    const int ldCol = (lane & 3) * 8;   // element offset (x2B = 16B)

    for (int kt = 0; kt < H_DIM / 32; ++kt) {
        const int kb = kt * 32;
        __syncthreads();
        if (wave == 0) {
            const uint16_t* g = Zfin + (size_t)(mBase + ldRow) * H_DIM + kb + ldCol;
            gload_lds16(g, &sA[0]);
        }
#pragma unroll
        for (int s = 0; s < 3; ++s) {
            const uint16_t* wsrc = OW3 + (size_t)s * O_DIM * H_DIM;
#pragma unroll
            for (int j = 0; j < 2; ++j) {
                const int rseg = j * 4 + wave;   // 0..7, 16 rows each
                const uint16_t* g = wsrc + (size_t)(rseg * 16 + ldRow) * H_DIM + kb + ldCol;
                gload_lds16(g, &sB[s][rseg * 16 * 32]);
            }
        }
        __syncthreads();

        bf16x8 aF = *reinterpret_cast<const bf16x8*>(&sA[col * 32 + quad * 8]);
#pragma unroll
        for (int s = 0; s < 3; ++s) {
#pragma unroll
            for (int ni = 0; ni < 2; ++ni) {
                int row = wave * 32 + ni * 16 + col;
                bf16x8 bF = *reinterpret_cast<const bf16x8*>(&sB[s][row * 32 + quad * 8]);
                acc[ni] = __builtin_amdgcn_mfma_f32_16x16x32_bf16(aF, bF, acc[ni], 0, 0, 0);
            }
        }
    }

    {
#pragma clang fp contract(off)
#pragma unroll
        for (int ni = 0; ni < 2; ++ni)
#pragma unroll
            for (int r = 0; r < 4; ++r) {
                int b = mBase + quad * 4 + r;          // C/D: row = quad*4 + reg
                int h = wave * 32 + ni * 16 + col;     //      col = lane&15
                out[(size_t)b * O_DIM + h] = acc[ni][r] + out_b[h];
            }
    }
}

extern "C" void kernel_launch(void* const* d_in, const int* in_sizes, int n_in,
                              void* d_out, int out_size, void* d_ws, size_t ws_size,
                              hipStream_t stream) {
    const float* x     = (const float*)d_in[0];
    const float* w_in  = (const float*)d_in[1];
    const float* w_rec = (const float*)d_in[2];
    const float* out_w = (const float*)d_in[3];
    const float* out_b = (const float*)d_in[4];
    float* out = (float*)d_out;

    char* ws = (char*)d_ws;
    size_t off = 0;
    int8_t*   WB   = (int8_t*)(ws + off);   off += (size_t)3 * H_DIM * K_TOT;        // 9.4 MB
    uint16_t* OW3  = (uint16_t*)(ws + off); off += (size_t)3 * O_DIM * H_DIM * 2;    // 0.8 MB
    int8_t*   Xall = (int8_t*)(ws + off);   off += (size_t)T_STEPS * B_DIM * I_DIM;  // 117 MB
    uint16_t* Zbf  = (uint16_t*)(ws + off); off += (size_t)B_DIM * H_DIM * 2;        // 8 MB
    int8_t*   ZS   = (int8_t*)(ws + off);   off += (size_t)13 * ZBYTES;              // 54.5 MB (per-step z)
    uint32_t* CNT  = (uint32_t*)(ws + off); off += (size_t)32 * 13 * 32 * 4;         // 53 KB

    split_w_kernel<<<(H_DIM * K_TOT) / 256, 256, 0, stream>>>(w_in, w_rec, WB);
    split_ow_kernel<<<(O_DIM * H_DIM) / 256, 256, 0, stream>>>(out_w, OW3);
    cvt_x_kernel<<<(int)(((size_t)T_STEPS * B_DIM * I_DIM / 16) / 256), 256, 0, stream>>>(x, Xall);
    zero_cnt_kernel<<<(32 * 13 * 32) / 256, 256, 0, stream>>>(CNT);

    // PLAIN launch: capture-safe. 512 blocks = 2/CU exact-fit (160KB LDS / 2 blocks).
    lif_persist_kernel<<<dim3(512), dim3(256), 0, stream>>>(Xall, WB, ZS, Zbf, CNT);

    out_gemm_kernel<<<B_DIM / 16, 256, 0, stream>>>(Zbf, OW3, out_b, out);
}

// Round 11
// 1200.330 us; speedup vs baseline: 1.1293x; 1.0102x over previous
//
#include <hip/hip_runtime.h>
#include <stdint.h>

#define T_STEPS 14
#define B_DIM   4096
#define I_DIM   2048
#define H_DIM   1024
#define O_DIM   128
#define K_TOT   3072   // I_DIM + H_DIM
#define ZBYTES  ((size_t)B_DIM * H_DIM)

// fixed-point scale 2^25: |w|max ~0.16 -> |W| ~5.1M, 3 signed base-256 digits exact
#define WSCALE_F 33554432.0f

typedef __bf16  bf16x8  __attribute__((ext_vector_type(8)));
typedef float   floatx4 __attribute__((ext_vector_type(4)));
typedef int     int4v   __attribute__((ext_vector_type(4)));
typedef int     int16v  __attribute__((ext_vector_type(16)));
typedef unsigned long long u64;

__device__ __forceinline__ uint16_t f2bf_rne(float f) {
    uint32_t u = __float_as_uint(f);
    u += 0x7fffu + ((u >> 16) & 1u);
    return (uint16_t)(u >> 16);
}
__device__ __forceinline__ float bf2f(uint16_t h) {
    return __uint_as_float(((uint32_t)h) << 16);
}

// async global->LDS, 16B/lane; LDS dest = wave-uniform base + lane*16 (implicit)
__device__ __forceinline__ void gload_lds16(const void* g, void* l) {
    __builtin_amdgcn_global_load_lds((__attribute__((address_space(1))) void*)g,
                                     (__attribute__((address_space(3))) void*)l, 16, 0, 0);
}

// ================= fragment-order layouts, BK=128 (validated r11) =================
// B digits: WB[nt(32)][ktw(24)][s(3)][kk(4)][lane(64)][16B]      (12 KB chunks)
// A spikes: Xall[t][mIdx(32)][ktx(16)][group(4)][kk(4)][lane(64)][16B]  (16 KB chunks)
// Z state:  ZS[t][mIdx(32)][ktz(8)][group(4)][kk(4)][lane(64)][16B]     (16 KB chunks)
// element (row = group*32 + (lane&31), k = kt*128 + kk*32 + (lane>>5)*16 + j)

__global__ void split_w_kernel(const float* __restrict__ w_in, const float* __restrict__ w_rec,
                               int8_t* __restrict__ WB) {
    int idx = blockIdx.x * 256 + threadIdx.x;          // over H_DIM*K_TOT
    int h = idx / K_TOT;
    int k = idx - h * K_TOT;
    float w = (k < I_DIM) ? w_in[(size_t)h * I_DIM + k]
                          : w_rec[(size_t)h * H_DIM + (k - I_DIM)];
    int W  = __float2int_rn(w * WSCALE_F);
    int d0 = (int8_t)(W & 0xFF);
    int r1 = (W - d0) >> 8;
    int d1 = (int8_t)(r1 & 0xFF);
    int d2 = (r1 - d1) >> 8;                           // |d2| <= ~80
    int nt = h >> 5, n32 = h & 31;
    int ktw = k >> 7, k128 = k & 127;
    int kk = k128 >> 5, half = (k128 >> 4) & 1, j = k128 & 15;
    int lane = half * 32 + n32;
    size_t base = (size_t)(nt * 24 + ktw) * 12288 + kk * 1024 + lane * 16 + j;
    WB[base] = (int8_t)d0; WB[base + 4096] = (int8_t)d1; WB[base + 8192] = (int8_t)d2;
}

// ---------- out_w -> bf16 hi/mid/lo (validated) ----------
__global__ void split_ow_kernel(const float* __restrict__ out_w, uint16_t* __restrict__ OW3) {
    int idx = blockIdx.x * 256 + threadIdx.x;          // over O_DIM*H_DIM
    float w = out_w[idx];
    uint16_t hi = f2bf_rne(w);
    float r1 = w - bf2f(hi);
    uint16_t mid = f2bf_rne(r1);
    float r2 = r1 - bf2f(mid);
    uint16_t lo = f2bf_rne(r2);
    const size_t S = (size_t)O_DIM * H_DIM;
    OW3[idx] = hi; OW3[idx + S] = mid; OW3[idx + 2 * S] = lo;
}

// ---------- x fp32 -> i8, ALL timesteps, BK=128 fragment-order (validated r11) ----------
__global__ void cvt_x_kernel(const float* __restrict__ x, int8_t* __restrict__ xb) {
    size_t gid = (size_t)blockIdx.x * 256 + threadIdx.x;   // one 16B output granule each
    int g = (int)(gid & 1023);                             // granule within 16KB chunk
    size_t chunk = gid >> 10;                              // (t*32 + mIdx)*16 + kt
    int kt   = (int)(chunk & 15);
    int mIdx = (int)((chunk >> 4) & 31);
    int t    = (int)(chunk >> 9);
    int group = g >> 8, kk = (g >> 6) & 3, lane = g & 63;
    int half = lane >> 5, row32 = lane & 31;
    int b = mIdx * 128 + group * 32 + row32;
    int k = kt * 128 + kk * 32 + half * 16;
    const float4* src = (const float4*)(x + ((size_t)t * B_DIM + b) * I_DIM + k);
    union { int8_t bytes[16]; int4v v; } u;
#pragma unroll
    for (int q = 0; q < 4; ++q) {
        float4 f = src[q];
        u.bytes[q * 4 + 0] = (int8_t)(f.x > 0.5f);
        u.bytes[q * 4 + 1] = (int8_t)(f.y > 0.5f);
        u.bytes[q * 4 + 2] = (int8_t)(f.z > 0.5f);
        u.bytes[q * 4 + 3] = (int8_t)(f.w > 0.5f);
    }
    ((int4v*)xb)[gid] = u.v;
}

// ---------- zero the group-sync counters ----------
__global__ void zero_cnt_kernel(uint32_t* __restrict__ cnt) {
    __hip_atomic_store(&cnt[blockIdx.x * 256 + threadIdx.x], 0u,
                       __ATOMIC_RELAXED, __HIP_MEMORY_SCOPE_AGENT);
}

// ====== R11: 64Mx32N waves — cut LDS reads per MFMA (the binding pipe) ======
// R10 post-mortem arithmetic: T_iter(CU)=4624cy; MFMA issue=1755cy (=38% MfmaUtil);
// LDS port = 304KB/CU-iter at ~85 B/cyc (m134 ds_read_b128) = ~3576cy -> the kernel
// is LDS-PORT-BOUND. Cause: all 4 waves read the same 24KB B (B-reuse=1/read).
// Fix: repartition waves 32Mx64N -> 64Mx32N. Per wave per kk: 2 A-frags + 3 B-frags
// feed 6 MFMA (each bF register reused for mf=0,1). Per-wave reads 28KB->20KB;
// per-CU-iter LDS 304KB->240KB (-21%). MFMA count, staging, vmcnt(10) ping-pong,
// ZS mapping, repack, flags: all byte-identical to validated R10.
__device__ __forceinline__ void stage_a(const int8_t* __restrict__ aC, int8_t* dst,
                                        int wave, int lane) {
#pragma unroll
    for (int j = 0; j < 4; ++j) {
        const int seg = j * 4 + wave;
        gload_lds16(aC + (size_t)seg * 1024 + lane * 16, dst + seg * 1024);
    }
}
__device__ __forceinline__ void stage_b(const int8_t* __restrict__ bA,
                                        const int8_t* __restrict__ bB,
                                        int8_t* dst, int wave, int lane) {
    gload_lds16(bA + (size_t)wave * 1024 + lane * 16,       dst + wave * 1024);
    gload_lds16(bA + (size_t)(4 + wave) * 1024 + lane * 16, dst + (4 + wave) * 1024);
    gload_lds16(bA + (size_t)(8 + wave) * 1024 + lane * 16, dst + (8 + wave) * 1024);
    gload_lds16(bB + (size_t)wave * 1024 + lane * 16,       dst + 12288 + wave * 1024);
    gload_lds16(bB + (size_t)(4 + wave) * 1024 + lane * 16, dst + 12288 + (4 + wave) * 1024);
    gload_lds16(bB + (size_t)(8 + wave) * 1024 + lane * 16, dst + 12288 + (8 + wave) * 1024);
}

__device__ __forceinline__ void lif_iter(const int8_t* __restrict__ aCn,   // A(kt+1) chunk or null
                                         const int8_t* __restrict__ bAn,   // B(kt+1) strip0 or null
                                         const int8_t* __restrict__ bBn,   // B(kt+1) strip1 or null
                                         const int8_t* curA, const int8_t* curB,
                                         int8_t* nxtA, int8_t* nxtB,
                                         int wave, int lane, bool stage_next,
                                         int16v (&acc)[2][3]) {
    if (stage_next) {
        stage_a(aCn, nxtA, wave, lane);
        stage_b(bAn, bBn, nxtB, wave, lane);
        __builtin_amdgcn_sched_barrier(0);
        asm volatile("s_waitcnt vmcnt(10)" ::: "memory");  // drain A(kt)+B(kt) stages; keep kt+1's 10
    } else {
        asm volatile("s_waitcnt vmcnt(0)" ::: "memory");   // tail: drain everything
    }
    __builtin_amdgcn_s_barrier();                          // all waves' A(kt)/B(kt) landed
    __builtin_amdgcn_sched_barrier(0);
    // wave (p = wave>>1, n = wave&1) owns rows [p*64, p*64+64) x strip n.
    // A-frag groups g = 2p+mf = (wave&~1)+mf; each bF feeds both mf MFMAs.
    const int gbase = wave & ~1;
    const int n = wave & 1;
    __builtin_amdgcn_s_setprio(1);                         // T5: favor MFMA-entering wave
#pragma unroll
    for (int kk = 0; kk < 4; ++kk) {
        int4v aF0 = *(const int4v*)(curA + gbase * 4096 + kk * 1024 + lane * 16);
        int4v aF1 = *(const int4v*)(curA + (gbase + 1) * 4096 + kk * 1024 + lane * 16);
#pragma unroll
        for (int s = 0; s < 3; ++s) {
            int4v bF = *(const int4v*)(curB + n * 12288 + s * 4096 + kk * 1024 + lane * 16);
            acc[0][s] = __builtin_amdgcn_mfma_i32_32x32x32_i8(aF0, bF, acc[0][s], 0, 0, 0);
            acc[1][s] = __builtin_amdgcn_mfma_i32_32x32x32_i8(aF1, bF, acc[1][s], 0, 0, 0);
        }
    }
    __builtin_amdgcn_s_setprio(0);
    asm volatile("s_waitcnt lgkmcnt(0)" ::: "memory");     // reads of cur done
    __builtin_amdgcn_s_barrier();                          // safe to overwrite cur next iter
}

// Contract: caller has ISSUED A(0)->sA0 and B(0)->sB0 (first iter's vmcnt(10) or an
// intervening __syncthreads completes them). NKT even: phase starts at buf0, last
// compute uses buf1, leaves buf0 free for the next phase's prologue.
template<int NKT>
__device__ __forceinline__ void run_phase(const int8_t* __restrict__ aC,   // A chunk base, +kt*16384
                                          const int8_t* __restrict__ bA,   // strip0 base, +kt*12288
                                          const int8_t* __restrict__ bB,   // strip1 base, +kt*12288
                                          int8_t* sA0, int8_t* sA1, int8_t* sB0, int8_t* sB1,
                                          int wave, int lane, int16v (&acc)[2][3]) {
#pragma unroll 1
    for (int kt = 0; kt + 2 < NKT; kt += 2) {
        lif_iter(aC + (size_t)(kt + 1) * 16384, bA + (size_t)(kt + 1) * 12288,
                 bB + (size_t)(kt + 1) * 12288, sA0, sB0, sA1, sB1, wave, lane, true, acc);
        lif_iter(aC + (size_t)(kt + 2) * 16384, bA + (size_t)(kt + 2) * 12288,
                 bB + (size_t)(kt + 2) * 12288, sA1, sB1, sA0, sB0, wave, lane, true, acc);
    }
    lif_iter(aC + (size_t)(NKT - 1) * 16384, bA + (size_t)(NKT - 1) * 12288,
             bB + (size_t)(NKT - 1) * 12288, sA0, sB0, sA1, sB1, wave, lane, true, acc);
    lif_iter(nullptr, nullptr, nullptr, sA1, sB1, sA0, sB0, wave, lane, false, acc);
}

// ================= persistent LIF: all 14 steps, ONE PLAIN launch =================
// Tile 128M x 64N, grid 512, 2 blocks/CU: LDS 80KB x2 = 160KB exact, VGPR <= 256
// (launch_bounds 256,2 -> 8 waves/CU). mIdx group = 16 blocks (flag target 16).
// XCD grouping: mIdx = (bid&7)*4 + (q&3), nt2 = q>>2.
// Coherence protocol — validated R6/R8/R9/R10 through the timed path (no fences):
//  - dispatch boundaries invalidate L2s (replay staleness handled);
//  - ZS[t] virgin until producers' agent-scope 8B stores (LLC write-through,
//    vmcnt-acked before flag add); consumers spin + __syncthreads -> cached loads fresh;
//  - flag spin: relaxed agent-scope loads (no invalidates, groups drift freely).
__launch_bounds__(256, 2)
__global__ void lif_persist_kernel(const int8_t* __restrict__ Xall,
                                   const int8_t* __restrict__ WB,
                                   int8_t* __restrict__ ZS,      // 13 per-step z buffers
                                   uint16_t* __restrict__ Zbf,
                                   uint32_t* __restrict__ cnt) {
    __shared__ int8_t sMem[81920];
    int8_t* const sA0 = sMem;               // 16 KB
    int8_t* const sA1 = sMem + 16384;       // 16 KB (sZ aliases here during epilogue)
    int8_t* const sB0 = sMem + 32768;       // 24 KB
    int8_t* const sB1 = sMem + 57344;       // 24 KB
    int8_t* const sZ  = sA1;                // dead at epilogue time (ordering audited)

    const int tid  = threadIdx.x;
    const int wave = tid >> 6, lane = tid & 63;
    const int lane32 = lane & 31, hl = lane >> 5;

    // group-per-XCD swizzle: 512 blocks, 64 per XCD = 4 mIdx x 16 nt2
    const int bid = blockIdx.x;
    const int xs = bid & 7, q = bid >> 3;       // q in 0..63
    const int mIdx = xs * 4 + (q & 3);
    const int nt2  = q >> 2;                    // 0..15, covers nt = 2*nt2, 2*nt2+1

    const int mBase = mIdx * 128, nBase = nt2 * 64;
    const int8_t* wbA = WB + (size_t)(2 * nt2) * 24 * 12288;
    const int8_t* wbB = WB + (size_t)(2 * nt2 + 1) * 24 * 12288;

    // wave partition: p = row-half (64 rows), n = strip
    const int p = wave >> 1, n = wave & 1;

    float vmem[2][16], isyn[2][16];
#pragma unroll
    for (int mf = 0; mf < 2; ++mf)
#pragma unroll
        for (int r = 0; r < 16; ++r) { vmem[mf][r] = 0.0f; isyn[mf][r] = 0.0f; }

    // initial prologue: X(t=0) A(0) + B(0) -> buf0 (first iter's vmcnt(10) drains)
    stage_a(Xall + (size_t)mIdx * 16 * 16384, sA0, wave, lane);
    stage_b(wbA, wbB, sB0, wave, lane);

    for (int t = 0; t < T_STEPS; ++t) {
        int16v acc[2][3] = {};   // [mf][digit]

        // ---- X phase: kt 0..15 (A(0)/B(0) already staged into buf0) ----
        const int8_t* XtC = Xall + (size_t)t * ((size_t)B_DIM * I_DIM)
                          + (size_t)mIdx * 16 * 16384;
        run_phase<16>(XtC, wbA, wbB, sA0, sA1, sB0, sB1, wave, lane, acc);

        // ---- recurrent phase: needs z(t-1) from the 16 blocks of this mIdx group ----
        if (t > 0) {
            const int8_t* zbA = wbA + (size_t)16 * 12288;
            const int8_t* zbB = wbB + (size_t)16 * 12288;
            stage_b(zbA, zbB, sB0, wave, lane);   // W independent of z: hide under spin
            if (tid == 0) {
                const uint32_t* f = cnt + ((size_t)mIdx * 13 + (t - 1)) * 32;
                while (__hip_atomic_load((uint32_t*)f, __ATOMIC_RELAXED, __HIP_MEMORY_SCOPE_AGENT) < 16u)
                    __builtin_amdgcn_s_sleep(2);
            }
            __syncthreads();   // spin visible; full barrier; drains B(0) stage
            const int8_t* zC = ZS + (size_t)(t - 1) * ZBYTES + (size_t)mIdx * 8 * 16384;
            stage_a(zC, sA0, wave, lane);         // z A(0); first iter's vmcnt(10) drains it
            run_phase<8>(zC, zbA, zbB, sA0, sA1, sB0, sB1, wave, lane, acc);
        }

        // ---- prestage NEXT step's X A(0)/B(0) into buf0 (free after even-NKT phase);
        //      latency hides under the epilogue; drained by epilogue __syncthreads ----
        if (t + 1 < T_STEPS) {
            stage_a(Xall + (size_t)(t + 1) * ((size_t)B_DIM * I_DIM)
                    + (size_t)mIdx * 16 * 16384, sA0, wave, lane);
            stage_b(wbA, wbB, sB0, wave, lane);
        }

        // ---- LIF epilogue (registers): C/D row=(r&3)+8*(r>>2)+4*hl, col=lane32 ----
#pragma unroll
        for (int mf = 0; mf < 2; ++mf) {
#pragma unroll
            for (int r = 0; r < 16; ++r) {
#pragma clang fp contract(off)
                // exact digit combine (|counts| < 2^24)
                float cur = (float)acc[mf][2][r] * (1.0f / 512.0f)
                          + (float)acc[mf][1][r] * (1.0f / 131072.0f)
                          + (float)acc[mf][0][r] * (1.0f / 33554432.0f);
                int row = (r & 3) + 8 * (r >> 2) + 4 * hl;    // 0..31 (C/D layout)
                float v_dec = vmem[mf][r] + 0.1f * ((0.0f - vmem[mf][r]) + isyn[mf][r]);
                float i_dec = isyn[mf][r] - 0.2f * isyn[mf][r];
                bool z = (v_dec > 1.0f);
                vmem[mf][r] = z ? 0.0f : v_dec;               // == (1-z)*v_dec + z*V_RESET exactly
                isyn[mf][r] = i_dec + cur;
                if (t == T_STEPS - 1) {
                    int b = mBase + p * 64 + mf * 32 + row;
                    int h = nBase + n * 32 + lane32;
                    Zbf[(size_t)b * H_DIM + h] = z ? (uint16_t)0x3F80 : (uint16_t)0;
                } else {
                    // sZ[strip][group=2p+mf][lane'*16+j] — same layout as R10
                    sZ[n * 4096 + ((wave & ~1) + mf) * 1024
                       + ((lane32 >> 4) * 32 + row) * 16 + (lane32 & 15)]
                        = z ? (int8_t)1 : (int8_t)0;
                }
            }
        }

        if (t < T_STEPS - 1) {
            __syncthreads();   // sZ complete; drains prestaged A/B (vmcnt 0)
            // repack: per strip, 16 contiguous bytes/thread -> two 8B agent-scope stores
#pragma unroll
            for (int ns = 0; ns < 2; ++ns) {
                const u64* sp = (const u64*)&sZ[ns * 4096 + tid * 16];
                u64 v0 = sp[0], v1 = sp[1];
                const int ntn = nt2 * 2 + ns;
                int8_t* dst = ZS + (size_t)t * ZBYTES + ((size_t)mIdx * 8 + (ntn >> 2)) * 16384
                            + (tid >> 6) * 4096 + (ntn & 3) * 1024 + (tid & 63) * 16;
                __hip_atomic_store((u64*)dst,       v0, __ATOMIC_RELAXED, __HIP_MEMORY_SCOPE_AGENT);
                __hip_atomic_store((u64*)(dst + 8), v1, __ATOMIC_RELAXED, __HIP_MEMORY_SCOPE_AGENT);
            }
            __syncthreads();   // all z-stores acked at the coherence point; sZ reads done
            if (tid == 0)
                __hip_atomic_fetch_add(&cnt[((size_t)mIdx * 13 + t) * 32], 1u,
                                       __ATOMIC_RELAXED, __HIP_MEMORY_SCOPE_AGENT);
        }
    }
}

// ---------- output GEMM: out = z_T @ out_w^T + out_b (bf16x3) ----------
__launch_bounds__(256)
__global__ void out_gemm_kernel(const uint16_t* __restrict__ Zfin,  // [B][H_DIM] bf16
                                const uint16_t* __restrict__ OW3,   // [3][O_DIM][H_DIM] bf16
                                const float* __restrict__ out_b,
                                float* __restrict__ out) {
    __shared__ uint16_t sA[16 * 32];        // 1 KB : [row(16)][k(32)]
    __shared__ uint16_t sB[3][128 * 32];    // 24 KB: [s][row(128)][k(32)]

    const int tid  = threadIdx.x;
    const int wave = tid >> 6, lane = tid & 63;
    const int quad = lane >> 4, col = lane & 15;

    const int mBase = blockIdx.x * 16;

    floatx4 acc[2] = {};

    const int ldRow = lane >> 2;        // 0..15
    const int ldCol = (lane & 3) * 8;   // element offset (x2B = 16B)

    for (int kt = 0; kt < H_DIM / 32; ++kt) {
        const int kb = kt * 32;
        __syncthreads();
        if (wave == 0) {
            const uint16_t* g = Zfin + (size_t)(mBase + ldRow) * H_DIM + kb + ldCol;
            gload_lds16(g, &sA[0]);
        }
#pragma unroll
        for (int s = 0; s < 3; ++s) {
            const uint16_t* wsrc = OW3 + (size_t)s * O_DIM * H_DIM;
#pragma unroll
            for (int j = 0; j < 2; ++j) {
                const int rseg = j * 4 + wave;   // 0..7, 16 rows each
                const uint16_t* g = wsrc + (size_t)(rseg * 16 + ldRow) * H_DIM + kb + ldCol;
                gload_lds16(g, &sB[s][rseg * 16 * 32]);
            }
        }
        __syncthreads();

        bf16x8 aF = *reinterpret_cast<const bf16x8*>(&sA[col * 32 + quad * 8]);
#pragma unroll
        for (int s = 0; s < 3; ++s) {
#pragma unroll
            for (int ni = 0; ni < 2; ++ni) {
                int row = wave * 32 + ni * 16 + col;
                bf16x8 bF = *reinterpret_cast<const bf16x8*>(&sB[s][row * 32 + quad * 8]);
                acc[ni] = __builtin_amdgcn_mfma_f32_16x16x32_bf16(aF, bF, acc[ni], 0, 0, 0);
            }
        }
    }

    {
#pragma clang fp contract(off)
#pragma unroll
        for (int ni = 0; ni < 2; ++ni)
#pragma unroll
            for (int r = 0; r < 4; ++r) {
                int b = mBase + quad * 4 + r;          // C/D: row = quad*4 + reg
                int h = wave * 32 + ni * 16 + col;     //      col = lane&15
                out[(size_t)b * O_DIM + h] = acc[ni][r] + out_b[h];
            }
    }
}

extern "C" void kernel_launch(void* const* d_in, const int* in_sizes, int n_in,
                              void* d_out, int out_size, void* d_ws, size_t ws_size,
                              hipStream_t stream) {
    const float* x     = (const float*)d_in[0];
    const float* w_in  = (const float*)d_in[1];
    const float* w_rec = (const float*)d_in[2];
    const float* out_w = (const float*)d_in[3];
    const float* out_b = (const float*)d_in[4];
    float* out = (float*)d_out;

    char* ws = (char*)d_ws;
    size_t off = 0;
    int8_t*   WB   = (int8_t*)(ws + off);   off += (size_t)3 * H_DIM * K_TOT;        // 9.4 MB
    uint16_t* OW3  = (uint16_t*)(ws + off); off += (size_t)3 * O_DIM * H_DIM * 2;    // 0.8 MB
    int8_t*   Xall = (int8_t*)(ws + off);   off += (size_t)T_STEPS * B_DIM * I_DIM;  // 117 MB
    uint16_t* Zbf  = (uint16_t*)(ws + off); off += (size_t)B_DIM * H_DIM * 2;        // 8 MB
    int8_t*   ZS   = (int8_t*)(ws + off);   off += (size_t)13 * ZBYTES;              // 54.5 MB (per-step z)
    uint32_t* CNT  = (uint32_t*)(ws + off); off += (size_t)32 * 13 * 32 * 4;         // 53 KB

    split_w_kernel<<<(H_DIM * K_TOT) / 256, 256, 0, stream>>>(w_in, w_rec, WB);
    split_ow_kernel<<<(O_DIM * H_DIM) / 256, 256, 0, stream>>>(out_w, OW3);
    cvt_x_kernel<<<(int)(((size_t)T_STEPS * B_DIM * I_DIM / 16) / 256), 256, 0, stream>>>(x, Xall);
    zero_cnt_kernel<<<(32 * 13 * 32) / 256, 256, 0, stream>>>(CNT);

    // PLAIN launch: capture-safe. 512 blocks = 2/CU exact-fit (160KB LDS / 2 blocks).
    lif_persist_kernel<<<dim3(512), dim3(256), 0, stream>>>(Xall, WB, ZS, Zbf, CNT);

    out_gemm_kernel<<<B_DIM / 16, 256, 0, stream>>>(Zbf, OW3, out_b, out);
}